// Round 11
// baseline (493.409 us; speedup 1.0000x reference)
//
#include <hip/hip_runtime.h>
#include <hip/hip_bf16.h>

typedef __attribute__((ext_vector_type(8))) short short8;
typedef __attribute__((ext_vector_type(4))) float f32x4;

#define DEVINL __device__ __forceinline__

constexpr int Bc = 4, Sc = 2048, Dc = 2048, Hc = 16, DHc = 128;
// softmax in exp2 space: Q pre-scaled by 1/sqrt(128) * log2(e) in its GEMM
constexpr float SCALE2 = 0.08838834764831845f * 1.4426950408889634f;

DEVINL float exp2s(float x) { return __builtin_amdgcn_exp2f(x); }

DEVINL short f2bf(float f) {
  unsigned u = __builtin_bit_cast(unsigned, f);
  u = (u + 0x7fffu + ((u >> 16) & 1u)) >> 16;
  return (short)u;
}
DEVINL unsigned pack2(float a, float b) {
  return (unsigned)(unsigned short)f2bf(a) | ((unsigned)(unsigned short)f2bf(b) << 16);
}

// async global->LDS, 16B per lane; LDS dest = wave-uniform base + lane*16
DEVINL void gload16(const void* g, void* l) {
  __builtin_amdgcn_global_load_lds(
      (const __attribute__((address_space(1))) void*)g,
      (__attribute__((address_space(3))) void*)l, 16, 0, 0);
}

// ---------------- weight transpose + fp32->bf16:  wt[n][k] = w[k][n] -------
__global__ __launch_bounds__(256) void transpose_w_kernel(
    const float* __restrict__ w0, const float* __restrict__ w1,
    const float* __restrict__ w2, const float* __restrict__ w3,
    short* __restrict__ wt) {
  __shared__ float tile[32][33];
  const float* w = (blockIdx.z == 0) ? w0 : (blockIdx.z == 1) ? w1
                   : (blockIdx.z == 2) ? w2 : w3;
  short* out = wt + (size_t)blockIdx.z * Dc * Dc;
  int k0 = blockIdx.x * 32, n0 = blockIdx.y * 32;
  int t = threadIdx.x;
#pragma unroll
  for (int p = 0; p < 4; ++p) {
    int idx = p * 256 + t;
    int kr = idx >> 5, nc = idx & 31;
    tile[kr][nc] = w[(size_t)(k0 + kr) * Dc + n0 + nc];
  }
  __syncthreads();
#pragma unroll
  for (int p = 0; p < 4; ++p) {
    int idx = p * 256 + t;
    int nr = idx >> 5, kc = idx & 31;
    out[(size_t)(n0 + nr) * Dc + k0 + kc] = f2bf(tile[kc][nr]);
  }
}

// ---------------- f32 -> bf16 convert (vectorized, grid-stride) ------------
__global__ __launch_bounds__(256) void convert_kernel(
    const float* __restrict__ in, short* __restrict__ out, int n8) {
  int stride = gridDim.x * 256;
  for (int idx = blockIdx.x * 256 + threadIdx.x; idx < n8; idx += stride) {
    const f32x4* p = (const f32x4*)(in + (size_t)idx * 8);
    f32x4 a = p[0], b = p[1];
    short8 r;
    r[0] = f2bf(a[0]); r[1] = f2bf(a[1]); r[2] = f2bf(a[2]); r[3] = f2bf(a[3]);
    r[4] = f2bf(b[0]); r[5] = f2bf(b[1]); r[6] = f2bf(b[2]); r[7] = f2bf(b[3]);
    *(short8*)(out + (size_t)idx * 8) = r;
  }
}

// ---------------- 256x256 ring GEMM: C = A[M,K] @ Wt[N,K]^T + bias ---------
// 8 waves (2M x 4N), BK=32, 4-slot LDS ring (slot = kt&3, 128 KiB).
// Template-style fine phases (m196/m201): per kt, TWO phases, each
// {ds_reads; stage issue; barrier; lgkmcnt(0); setprio; 16 MFMA; setprio;
// barrier}. Counted vmcnt(8) once per kt at phase B: history ...A(kt+2),
// B(kt+2), A(kt+3), B(kt+3) = last 8 loads -> proves stage(kt+1) complete
// while 8 loads stay in flight (T4, never 0 in steady state).
// Slot safety: stage(kt+3) writes slot (kt-1)&3 whose last read (af2, kt-1
// phase B) is barrier-ordered before any kt-phase-A issue.
// __launch_bounds__(512,1): LDS-bound 1 block/CU -> full 256-VGPR budget.
// LDS swizzle: 16B slot s at row r stored at s ^ ((r>>1)&3) -> even banks.
// OUT_MODE: 0 = bf16 [M,N] (scaled), 1 = f32 [M,N], 2 = bf16 VT [B,H,DH,S]
template <int OUT_MODE>
__global__ __launch_bounds__(512, 1) void gemm_ring_kernel(
    const short* __restrict__ A, const short* __restrict__ Wt,
    const float* __restrict__ bias, void* __restrict__ Cptr, float oscale) {
  __shared__ __align__(16) short As[4][256 * 32];
  __shared__ __align__(16) short Bs[4][256 * 32];
  const int tid = threadIdx.x, lane = tid & 63, wid = tid >> 6;
  const int wm = wid >> 2, wn = wid & 3;
  const int lr = lane & 15, g = lane >> 4;
  const int physg = (g ^ ((lr >> 1) & 3)) * 8;  // swizzled read col (shorts)

  // XCD-aware bijective swizzle: 256 blocks, 8 XCDs, 32 per XCD
  const int bid = blockIdx.x;
  const int swz = (bid & 7) * 32 + (bid >> 3);
  const int m0 = (swz >> 3) * 256, n0 = (swz & 7) * 256;

  // staging: wave stages rows wid*32..wid*32+31 (2 gloads per tensor per kt)
  const int srow = lane >> 2;                             // 0..15
  const int scol = ((lane & 3) ^ ((lane >> 3) & 3)) * 8;  // pre-swizzled src
  const size_t abase = (size_t)(m0 + wid * 32 + srow) * Dc + scol;
  const size_t bbase = (size_t)(n0 + wid * 32 + srow) * Dc + scol;
  const int ldof = wid * 32 * 64;  // byte offset of wave's row block

  auto stageA = [&](int kt) {
    const short* src = &A[abase + kt * 32];
    char* dst = (char*)&As[kt & 3][0] + ldof;
    gload16(src, dst);
    gload16(src + (size_t)16 * Dc, dst + 16 * 64);
  };
  auto stageB = [&](int kt) {
    const short* src = &Wt[bbase + kt * 32];
    char* dst = (char*)&Bs[kt & 3][0] + ldof;
    gload16(src, dst);
    gload16(src + (size_t)16 * Dc, dst + 16 * 64);
  };

  f32x4 acc[8][4] = {};

  stageA(0); stageB(0);
  stageA(1); stageB(1);
  stageA(2); stageB(2);
  asm volatile("s_waitcnt vmcnt(8)" ::: "memory");  // kt=0 tiles complete
  __builtin_amdgcn_s_barrier();
  asm volatile("" ::: "memory");

  for (int kt = 0; kt < 64; ++kt) {
    const short* Ab = &As[kt & 3][0];
    const short* Bb = &Bs[kt & 3][0];
    short8 afr[4], bfr[4], af2[4];

    // ======== phase A: reads for MFMA block 1 + stage A(kt+3) ========
#pragma unroll
    for (int i = 0; i < 4; ++i)
      afr[i] = *(const short8*)&Ab[(wm * 128 + i * 16 + lr) * 32 + physg];
#pragma unroll
    for (int j = 0; j < 4; ++j)
      bfr[j] = *(const short8*)&Bb[(wn * 64 + j * 16 + lr) * 32 + physg];
    if (kt <= 60) stageA(kt + 3);
    __builtin_amdgcn_s_barrier();
    asm volatile("s_waitcnt lgkmcnt(0)" ::: "memory");
    __builtin_amdgcn_sched_barrier(0);
    __builtin_amdgcn_s_setprio(1);
#pragma unroll
    for (int i = 0; i < 4; ++i)
#pragma unroll
      for (int j = 0; j < 4; ++j)
        acc[i][j] = __builtin_amdgcn_mfma_f32_16x16x32_bf16(afr[i], bfr[j], acc[i][j], 0, 0, 0);
    __builtin_amdgcn_s_setprio(0);
    __builtin_amdgcn_s_barrier();

    // ======== phase B: reads for MFMA block 2 + stage B(kt+3) ========
#pragma unroll
    for (int i = 0; i < 4; ++i)
      af2[i] = *(const short8*)&Ab[(wm * 128 + 64 + i * 16 + lr) * 32 + physg];
    if (kt <= 60) stageB(kt + 3);
    // counted wait: prove stage(kt+1) fully landed; keep 8 loads in flight
    if (kt <= 60) {
      asm volatile("s_waitcnt vmcnt(8)" ::: "memory");
    } else if (kt == 61) {
      asm volatile("s_waitcnt vmcnt(4)" ::: "memory");
    } else if (kt == 62) {
      asm volatile("s_waitcnt vmcnt(0)" ::: "memory");
    }
    __builtin_amdgcn_s_barrier();
    asm volatile("s_waitcnt lgkmcnt(0)" ::: "memory");
    __builtin_amdgcn_sched_barrier(0);
    __builtin_amdgcn_s_setprio(1);
#pragma unroll
    for (int i = 0; i < 4; ++i)
#pragma unroll
      for (int j = 0; j < 4; ++j)
        acc[4 + i][j] = __builtin_amdgcn_mfma_f32_16x16x32_bf16(af2[i], bfr[j], acc[4 + i][j], 0, 0, 0);
    __builtin_amdgcn_s_setprio(0);
    __builtin_amdgcn_s_barrier();
  }

  const int rowl = g * 4;
#pragma unroll
  for (int bj = 0; bj < 4; ++bj) {
    const int gcol = n0 + wn * 64 + bj * 16 + lr;
    const float bv = bias[gcol];
#pragma unroll
    for (int ai = 0; ai < 8; ++ai) {
#pragma unroll
      for (int r = 0; r < 4; ++r) {
        int grow = m0 + wm * 128 + ai * 16 + rowl + r;
        float v = (acc[ai][bj][r] + bv) * oscale;
        if (OUT_MODE == 1) {
          ((float*)Cptr)[(size_t)grow * Dc + gcol] = v;
        } else if (OUT_MODE == 0) {
          ((short*)Cptr)[(size_t)grow * Dc + gcol] = f2bf(v);
        } else {
          int b4 = grow >> 11, ss = grow & (Sc - 1);
          int hh = gcol >> 7, dh = gcol & (DHc - 1);
          ((short*)Cptr)[((((size_t)(b4 * Hc + hh) * DHc) + dh) << 11) + ss] = f2bf(v);
        }
      }
    }
  }
}

// ---------------- flash attention (causal), QB=256, 8 waves ----------------
// Swapped QK^T (lane owns q-rows) + T14 reg-staging + T13 defer-max.
// Q pre-scaled by SCALE2 in its projection -> scores already in log2 space.
// LDS XOR-swizzled 16B slots: Ks[row][s^=(row&7)], Vs[d][s^=(d&7)].
__global__ __launch_bounds__(512, 2) void attn_kernel(
    const short* __restrict__ qp, const short* __restrict__ kp,
    const short* __restrict__ vt, short* __restrict__ attn) {
  __shared__ __align__(16) short Ks[64 * 128];
  __shared__ __align__(16) short Vs[128 * 64];
  __shared__ __align__(16) short Ps[8][32][72];
  const int tid = threadIdx.x, lane = tid & 63, wid = tid >> 6;
  const int lr = lane & 15, g = lane >> 4, lk = g * 8, rowl = g * 4;
  const int d = blockIdx.x;
  const int xcd = d & 7, s = d >> 3;
  const int grp = s >> 3;
  const int qi = (grp < 4) ? grp : 11 - grp;  // 0,1,2,3,7,6,5,4
  const int bh = xcd * 8 + (s & 7);
  const int b = bh >> 4, h = bh & 15;
  const int qb = qi * 256;
  const size_t headq = ((size_t)b * Sc) * Dc + (size_t)h * DHc;
  const size_t vbase = (((size_t)b * Hc + h) * DHc) << 11;
  const int qw = qb + wid * 32;
  const int x7 = lr & 7;

  short8 qf[2][4];
#pragma unroll
  for (int qs = 0; qs < 2; ++qs)
#pragma unroll
    for (int c = 0; c < 4; ++c)
      qf[qs][c] = *(const short8*)&qp[headq + (size_t)(qw + qs * 16 + lr) * Dc + c * 32 + lk];

  const int krow = wid * 4 + g;
  const int kcol = lr * 8;
  const int vrow = wid * 8 + (lane >> 3);
  const int vcol = (lane & 7) * 8;
  int kdst[2], vdst[2];
#pragma unroll
  for (int p = 0; p < 2; ++p) {
    int kr = p * 32 + krow;
    kdst[p] = kr * 128 + ((lr ^ (kr & 7)) * 8);
    int vr = p * 64 + vrow;
    vdst[p] = vr * 64 + (((lane & 7) ^ (vr & 7)) * 8);
  }

  short8 kreg[2], vreg[2];
  auto issue = [&](int kvb) {
#pragma unroll
    for (int p = 0; p < 2; ++p)
      kreg[p] = *(const short8*)&kp[headq + (size_t)(kvb + p * 32 + krow) * Dc + kcol];
#pragma unroll
    for (int p = 0; p < 2; ++p)
      vreg[p] = *(const short8*)&vt[vbase + (size_t)(p * 64 + vrow) * Sc + kvb + vcol];
  };
  auto commit = [&]() {
#pragma unroll
    for (int p = 0; p < 2; ++p) *(short8*)&Ks[kdst[p]] = kreg[p];
#pragma unroll
    for (int p = 0; p < 2; ++p) *(short8*)&Vs[vdst[p]] = vreg[p];
  };

  issue(0);
  commit();
  __syncthreads();

  f32x4 o[2][8] = {};
  float mrun[2] = {-1e30f, -1e30f}, lrun[2] = {0.f, 0.f};
  const int ntiles = qb / 64 + 4;

  for (int t = 0; t < ntiles; ++t) {
    const bool active = (64 * t <= qw + 31);  // wave-uniform
    f32x4 sc[2][4];

    if (active) {
      __builtin_amdgcn_s_setprio(1);
#pragma unroll
      for (int nb = 0; nb < 4; ++nb) {
        f32x4 s0 = {}, s1 = {};
#pragma unroll
        for (int c = 0; c < 4; ++c) {
          short8 kf = *(const short8*)&Ks[(nb * 16 + lr) * 128 + (((c * 4 + g) ^ x7) << 3)];
          s0 = __builtin_amdgcn_mfma_f32_16x16x32_bf16(kf, qf[0][c], s0, 0, 0, 0);
          s1 = __builtin_amdgcn_mfma_f32_16x16x32_bf16(kf, qf[1][c], s1, 0, 0, 0);
        }
        sc[0][nb] = s0;
        sc[1][nb] = s1;
      }
      __builtin_amdgcn_s_setprio(0);
    }

    if (t + 1 < ntiles) issue((t + 1) * 64);

    if (active) {
      const bool domask = (64 * t + 63 > qw);
#pragma unroll
      for (int qs = 0; qs < 2; ++qs) {
        const int qg = qw + qs * 16 + lr;
        float mnb[4];
#pragma unroll
        for (int nb = 0; nb < 4; ++nb) {
          if (domask) {
#pragma unroll
            for (int r = 0; r < 4; ++r) {
              int kv = t * 64 + nb * 16 + rowl + r;
              if (kv > qg) sc[qs][nb][r] = -1e30f;
            }
          }
          mnb[nb] = fmaxf(fmaxf(sc[qs][nb][0], sc[qs][nb][1]),
                          fmaxf(sc[qs][nb][2], sc[qs][nb][3]));
        }
        float mt = fmaxf(fmaxf(mnb[0], mnb[1]), fmaxf(mnb[2], mnb[3]));
        mt = fmaxf(mt, __shfl_xor(mt, 16));
        mt = fmaxf(mt, __shfl_xor(mt, 32));

        // T13 defer-max: only rescale when tile max exceeds running max + 8
        if (!__all(mt <= mrun[qs] + 8.f)) {
          float mnew = fmaxf(mrun[qs], mt);
          float alpha = exp2s(mrun[qs] - mnew);
          mrun[qs] = mnew;
          lrun[qs] *= alpha;
          float al[4];
#pragma unroll
          for (int r = 0; r < 4; ++r) al[r] = __shfl(alpha, (lane & 48) | (rowl + r));
#pragma unroll
          for (int f = 0; f < 8; ++f)
#pragma unroll
            for (int r = 0; r < 4; ++r) o[qs][f][r] *= al[r];
        }
        const float mcur = mrun[qs];

        float lsnb[4];
#pragma unroll
        for (int nb = 0; nb < 4; ++nb) {
          float p0 = exp2s(sc[qs][nb][0] - mcur);
          float p1 = exp2s(sc[qs][nb][1] - mcur);
          float p2 = exp2s(sc[qs][nb][2] - mcur);
          float p3 = exp2s(sc[qs][nb][3] - mcur);
          lsnb[nb] = (p0 + p1) + (p2 + p3);
          uint2 w;
          w.x = pack2(p0, p1);
          w.y = pack2(p2, p3);
          *(uint2*)&Ps[wid][qs * 16 + lr][nb * 16 + rowl] = w;
        }
        float ls = (lsnb[0] + lsnb[1]) + (lsnb[2] + lsnb[3]);
        ls += __shfl_xor(ls, 16);
        ls += __shfl_xor(ls, 32);
        lrun[qs] += ls;
      }

      asm volatile("s_waitcnt lgkmcnt(0)" ::: "memory");
      __builtin_amdgcn_sched_barrier(0);

      __builtin_amdgcn_s_setprio(1);
#pragma unroll
      for (int kc = 0; kc < 2; ++kc) {
        short8 pf0 = *(const short8*)&Ps[wid][lr][kc * 32 + lk];
        short8 pf1 = *(const short8*)&Ps[wid][16 + lr][kc * 32 + lk];
#pragma unroll
        for (int nb = 0; nb < 8; ++nb) {
          short8 vf = *(const short8*)&Vs[(nb * 16 + lr) * 64 + (((kc * 4 + g) ^ x7) << 3)];
          o[0][nb] = __builtin_amdgcn_mfma_f32_16x16x32_bf16(pf0, vf, o[0][nb], 0, 0, 0);
          o[1][nb] = __builtin_amdgcn_mfma_f32_16x16x32_bf16(pf1, vf, o[1][nb], 0, 0, 0);
        }
      }
      __builtin_amdgcn_s_setprio(0);
    }

    __syncthreads();
    if (t + 1 < ntiles) commit();
    __syncthreads();
  }

#pragma unroll
  for (int qs = 0; qs < 2; ++qs) {
    float ld[4];
#pragma unroll
    for (int r = 0; r < 4; ++r) ld[r] = __shfl(lrun[qs], (lane & 48) | (rowl + r));
#pragma unroll
    for (int f = 0; f < 8; ++f)
#pragma unroll
      for (int r = 0; r < 4; ++r) {
        float v = o[qs][f][r] / ld[r];
        attn[headq + (size_t)(qw + qs * 16 + rowl + r) * Dc + f * 16 + lr] = f2bf(v);
      }
  }
}

// ---------------------------------------------------------------------------
extern "C" void kernel_launch(void* const* d_in, const int* in_sizes, int n_in,
                              void* d_out, int out_size, void* d_ws, size_t ws_size,
                              hipStream_t stream) {
  const float* Q = (const float*)d_in[0];
  const float* K = (const float*)d_in[1];
  const float* V = (const float*)d_in[2];
  // d_in[3] = mask (causal tril, structural — unused)
  const float* wq = (const float*)d_in[4];
  const float* bq = (const float*)d_in[5];
  const float* wk = (const float*)d_in[6];
  const float* bk = (const float*)d_in[7];
  const float* wv = (const float*)d_in[8];
  const float* bv = (const float*)d_in[9];
  const float* wo = (const float*)d_in[10];
  const float* bo = (const float*)d_in[11];

  char* ws = (char*)d_ws;
  const size_t WSZ = (size_t)Dc * Dc;
  const size_t XSZ = (size_t)Bc * Sc * Dc;
  short* WT = (short*)ws;
  short* QP = (short*)(ws + 4 * WSZ * 2);
  short* KP = (short*)(ws + 4 * WSZ * 2 + XSZ * 2);
  short* VT = (short*)(ws + 4 * WSZ * 2 + 2 * XSZ * 2);
  short* AT = (short*)(ws + 4 * WSZ * 2 + 3 * XSZ * 2);  // conv scratch + attn out
  // total: 8*WSZ + 8*XSZ bytes = 32 MiB + 128 MiB = 160 MiB

  transpose_w_kernel<<<dim3(Dc / 32, Dc / 32, 4), 256, 0, stream>>>(wq, wk, wv, wo, WT);

  const int n8 = (int)(XSZ / 8);
  const int ng = (Bc * Sc / 256) * (Dc / 256);  // 256 blocks

  convert_kernel<<<2048, 256, 0, stream>>>(Q, AT, n8);
  gemm_ring_kernel<0><<<ng, 512, 0, stream>>>(AT, WT, bq, QP, SCALE2);
  convert_kernel<<<2048, 256, 0, stream>>>(K, AT, n8);
  gemm_ring_kernel<0><<<ng, 512, 0, stream>>>(AT, WT + WSZ, bk, KP, 1.f);
  convert_kernel<<<2048, 256, 0, stream>>>(V, AT, n8);
  gemm_ring_kernel<2><<<ng, 512, 0, stream>>>(AT, WT + 2 * WSZ, bv, VT, 1.f);

  attn_kernel<<<512, 512, 0, stream>>>(QP, KP, VT, AT);

  gemm_ring_kernel<1><<<ng, 512, 0, stream>>>(AT, WT + 3 * WSZ, bo, (float*)d_out, 1.f);
}

// Round 12
// 470.595 us; speedup vs baseline: 1.0485x; 1.0485x over previous
//
#include <hip/hip_runtime.h>
#include <hip/hip_bf16.h>

typedef __attribute__((ext_vector_type(8))) short short8;
typedef __attribute__((ext_vector_type(4))) float f32x4;

#define DEVINL __device__ __forceinline__

constexpr int Bc = 4, Sc = 2048, Dc = 2048, Hc = 16, DHc = 128;
// softmax in exp2 space: Q pre-scaled by 1/sqrt(128) * log2(e) in its GEMM
constexpr float SCALE2 = 0.08838834764831845f * 1.4426950408889634f;

DEVINL float exp2s(float x) { return __builtin_amdgcn_exp2f(x); }

DEVINL short f2bf(float f) {
  unsigned u = __builtin_bit_cast(unsigned, f);
  u = (u + 0x7fffu + ((u >> 16) & 1u)) >> 16;
  return (short)u;
}
DEVINL unsigned pack2(float a, float b) {
  return (unsigned)(unsigned short)f2bf(a) | ((unsigned)(unsigned short)f2bf(b) << 16);
}

// async global->LDS, 16B per lane; LDS dest = wave-uniform base + lane*16
DEVINL void gload16(const void* g, void* l) {
  __builtin_amdgcn_global_load_lds(
      (const __attribute__((address_space(1))) void*)g,
      (__attribute__((address_space(3))) void*)l, 16, 0, 0);
}

// ---------------- weight transpose + fp32->bf16:  wt[n][k] = w[k][n] -------
__global__ __launch_bounds__(256) void transpose_w_kernel(
    const float* __restrict__ w0, const float* __restrict__ w1,
    const float* __restrict__ w2, const float* __restrict__ w3,
    short* __restrict__ wt) {
  __shared__ float tile[32][33];
  const float* w = (blockIdx.z == 0) ? w0 : (blockIdx.z == 1) ? w1
                   : (blockIdx.z == 2) ? w2 : w3;
  short* out = wt + (size_t)blockIdx.z * Dc * Dc;
  int k0 = blockIdx.x * 32, n0 = blockIdx.y * 32;
  int t = threadIdx.x;
#pragma unroll
  for (int p = 0; p < 4; ++p) {
    int idx = p * 256 + t;
    int kr = idx >> 5, nc = idx & 31;
    tile[kr][nc] = w[(size_t)(k0 + kr) * Dc + n0 + nc];
  }
  __syncthreads();
#pragma unroll
  for (int p = 0; p < 4; ++p) {
    int idx = p * 256 + t;
    int nr = idx >> 5, kc = idx & 31;
    out[(size_t)(n0 + nr) * Dc + k0 + kc] = f2bf(tile[kc][nr]);
  }
}

// ---------------- f32 -> bf16 convert (vectorized, grid-stride) ------------
__global__ __launch_bounds__(256) void convert_kernel(
    const float* __restrict__ in, short* __restrict__ out, int n8) {
  int stride = gridDim.x * 256;
  for (int idx = blockIdx.x * 256 + threadIdx.x; idx < n8; idx += stride) {
    const f32x4* p = (const f32x4*)(in + (size_t)idx * 8);
    f32x4 a = p[0], b = p[1];
    short8 r;
    r[0] = f2bf(a[0]); r[1] = f2bf(a[1]); r[2] = f2bf(a[2]); r[3] = f2bf(a[3]);
    r[4] = f2bf(b[0]); r[5] = f2bf(b[1]); r[6] = f2bf(b[2]); r[7] = f2bf(b[3]);
    *(short8*)(out + (size_t)idx * 8) = r;
  }
}

// ---------------- 256x256 ring GEMM (round-9 proven, + oscale) -------------
// 8 waves (2M x 4N), BK=32, 4-slot LDS ring (slot = kt&3, 128 KiB).
// ONE barrier + ONE counted vmcnt per kt (32 MFMA): vmcnt(8)-then-barrier
// proves all waves' stage(kt) landed; slot reuse is 4 kt away. Compiler
// emits fine-grained lgkm waits for ds_read->MFMA.
// __launch_bounds__(512,1): LDS-bound 1 block/CU -> full 256-VGPR budget.
// LDS swizzle: 16B slot s at row r stored at s ^ ((r>>1)&3).
// OUT_MODE: 0 = bf16 [M,N] (scaled), 1 = f32 [M,N], 2 = bf16 VT [B,H,DH,S]
template <int OUT_MODE>
__global__ __launch_bounds__(512, 1) void gemm_ring_kernel(
    const short* __restrict__ A, const short* __restrict__ Wt,
    const float* __restrict__ bias, void* __restrict__ Cptr, float oscale) {
  __shared__ __align__(16) short As[4][256 * 32];
  __shared__ __align__(16) short Bs[4][256 * 32];
  const int tid = threadIdx.x, lane = tid & 63, wid = tid >> 6;
  const int wm = wid >> 2, wn = wid & 3;
  const int lr = lane & 15, g = lane >> 4;
  const int physg = (g ^ ((lr >> 1) & 3)) * 8;  // swizzled read col (shorts)

  // XCD-aware bijective swizzle: 256 blocks, 8 XCDs, 32 per XCD
  const int bid = blockIdx.x;
  const int swz = (bid & 7) * 32 + (bid >> 3);
  const int m0 = (swz >> 3) * 256, n0 = (swz & 7) * 256;

  // staging: wave stages rows wid*32..wid*32+31 (2 gloads per tensor per kt)
  const int srow = lane >> 2;                             // 0..15
  const int scol = ((lane & 3) ^ ((lane >> 3) & 3)) * 8;  // pre-swizzled src
  const size_t abase = (size_t)(m0 + wid * 32 + srow) * Dc + scol;
  const size_t bbase = (size_t)(n0 + wid * 32 + srow) * Dc + scol;
  const int ldof = wid * 32 * 64;  // byte offset of wave's row block

  auto stageA = [&](int kt) {
    const short* src = &A[abase + kt * 32];
    char* dst = (char*)&As[kt & 3][0] + ldof;
    gload16(src, dst);
    gload16(src + (size_t)16 * Dc, dst + 16 * 64);
  };
  auto stageB = [&](int kt) {
    const short* src = &Wt[bbase + kt * 32];
    char* dst = (char*)&Bs[kt & 3][0] + ldof;
    gload16(src, dst);
    gload16(src + (size_t)16 * Dc, dst + 16 * 64);
  };

  f32x4 acc[8][4] = {};

  stageA(0); stageB(0);
  stageA(1); stageB(1);
  stageA(2); stageB(2);

  for (int kt = 0; kt < 64; ++kt) {
    // counted wait: own stage(kt) done; barrier => ALL waves' stage(kt) done.
    // keeps stage(kt+1), stage(kt+2) [, stage(kt+3)] in flight across barrier.
    if (kt < 62) {
      asm volatile("s_waitcnt vmcnt(8)" ::: "memory");
    } else if (kt == 62) {
      asm volatile("s_waitcnt vmcnt(4)" ::: "memory");
    } else {
      asm volatile("s_waitcnt vmcnt(0)" ::: "memory");
    }
    __builtin_amdgcn_s_barrier();
    asm volatile("" ::: "memory");  // reads may not hoist above the barrier

    const short* Ab = &As[kt & 3][0];
    const short* Bb = &Bs[kt & 3][0];
    short8 afr[4], bfr[4], af2[4];
#pragma unroll
    for (int i = 0; i < 4; ++i)
      afr[i] = *(const short8*)&Ab[(wm * 128 + i * 16 + lr) * 32 + physg];
#pragma unroll
    for (int j = 0; j < 4; ++j)
      bfr[j] = *(const short8*)&Bb[(wn * 64 + j * 16 + lr) * 32 + physg];
#pragma unroll
    for (int i = 0; i < 4; ++i)
      af2[i] = *(const short8*)&Ab[(wm * 128 + 64 + i * 16 + lr) * 32 + physg];

    if (kt <= 60) { stageA(kt + 3); stageB(kt + 3); }  // writes slot (kt-1)&3

    __builtin_amdgcn_s_setprio(1);
#pragma unroll
    for (int i = 0; i < 4; ++i)
#pragma unroll
      for (int j = 0; j < 4; ++j)
        acc[i][j] = __builtin_amdgcn_mfma_f32_16x16x32_bf16(afr[i], bfr[j], acc[i][j], 0, 0, 0);
#pragma unroll
    for (int i = 0; i < 4; ++i)
#pragma unroll
      for (int j = 0; j < 4; ++j)
        acc[4 + i][j] = __builtin_amdgcn_mfma_f32_16x16x32_bf16(af2[i], bfr[j], acc[4 + i][j], 0, 0, 0);
    __builtin_amdgcn_s_setprio(0);
  }

  const int rowl = g * 4;
#pragma unroll
  for (int bj = 0; bj < 4; ++bj) {
    const int gcol = n0 + wn * 64 + bj * 16 + lr;
    const float bv = bias[gcol];
#pragma unroll
    for (int ai = 0; ai < 8; ++ai) {
#pragma unroll
      for (int r = 0; r < 4; ++r) {
        int grow = m0 + wm * 128 + ai * 16 + rowl + r;
        float v = (acc[ai][bj][r] + bv) * oscale;
        if (OUT_MODE == 1) {
          ((float*)Cptr)[(size_t)grow * Dc + gcol] = v;
        } else if (OUT_MODE == 0) {
          ((short*)Cptr)[(size_t)grow * Dc + gcol] = f2bf(v);
        } else {
          int b4 = grow >> 11, ss = grow & (Sc - 1);
          int hh = gcol >> 7, dh = gcol & (DHc - 1);
          ((short*)Cptr)[((((size_t)(b4 * Hc + hh) * DHc) + dh) << 11) + ss] = f2bf(v);
        }
      }
    }
  }
}

// ---------------- flash attention (causal), QB=256, 8 waves ----------------
// Swapped QK^T (lane owns q-rows) + T14 reg-staging + T13 defer-max.
// Q pre-scaled by SCALE2 in its projection -> scores already in log2 space.
// LDS XOR-swizzled 16B slots: Ks[row][s^=(row&7)], Vs[d][s^=(d&7)].
__global__ __launch_bounds__(512, 2) void attn_kernel(
    const short* __restrict__ qp, const short* __restrict__ kp,
    const short* __restrict__ vt, short* __restrict__ attn) {
  __shared__ __align__(16) short Ks[64 * 128];
  __shared__ __align__(16) short Vs[128 * 64];
  __shared__ __align__(16) short Ps[8][32][72];
  const int tid = threadIdx.x, lane = tid & 63, wid = tid >> 6;
  const int lr = lane & 15, g = lane >> 4, lk = g * 8, rowl = g * 4;
  const int d = blockIdx.x;
  const int xcd = d & 7, s = d >> 3;
  const int grp = s >> 3;
  const int qi = (grp < 4) ? grp : 11 - grp;  // 0,1,2,3,7,6,5,4
  const int bh = xcd * 8 + (s & 7);
  const int b = bh >> 4, h = bh & 15;
  const int qb = qi * 256;
  const size_t headq = ((size_t)b * Sc) * Dc + (size_t)h * DHc;
  const size_t vbase = (((size_t)b * Hc + h) * DHc) << 11;
  const int qw = qb + wid * 32;
  const int x7 = lr & 7;

  short8 qf[2][4];
#pragma unroll
  for (int qs = 0; qs < 2; ++qs)
#pragma unroll
    for (int c = 0; c < 4; ++c)
      qf[qs][c] = *(const short8*)&qp[headq + (size_t)(qw + qs * 16 + lr) * Dc + c * 32 + lk];

  const int krow = wid * 4 + g;
  const int kcol = lr * 8;
  const int vrow = wid * 8 + (lane >> 3);
  const int vcol = (lane & 7) * 8;
  int kdst[2], vdst[2];
#pragma unroll
  for (int p = 0; p < 2; ++p) {
    int kr = p * 32 + krow;
    kdst[p] = kr * 128 + ((lr ^ (kr & 7)) * 8);
    int vr = p * 64 + vrow;
    vdst[p] = vr * 64 + (((lane & 7) ^ (vr & 7)) * 8);
  }

  short8 kreg[2], vreg[2];
  auto issue = [&](int kvb) {
#pragma unroll
    for (int p = 0; p < 2; ++p)
      kreg[p] = *(const short8*)&kp[headq + (size_t)(kvb + p * 32 + krow) * Dc + kcol];
#pragma unroll
    for (int p = 0; p < 2; ++p)
      vreg[p] = *(const short8*)&vt[vbase + (size_t)(p * 64 + vrow) * Sc + kvb + vcol];
  };
  auto commit = [&]() {
#pragma unroll
    for (int p = 0; p < 2; ++p) *(short8*)&Ks[kdst[p]] = kreg[p];
#pragma unroll
    for (int p = 0; p < 2; ++p) *(short8*)&Vs[vdst[p]] = vreg[p];
  };

  issue(0);
  commit();
  __syncthreads();

  f32x4 o[2][8] = {};
  float mrun[2] = {-1e30f, -1e30f}, lrun[2] = {0.f, 0.f};
  const int ntiles = qb / 64 + 4;

  for (int t = 0; t < ntiles; ++t) {
    const bool active = (64 * t <= qw + 31);  // wave-uniform
    f32x4 sc[2][4];

    if (active) {
      __builtin_amdgcn_s_setprio(1);
#pragma unroll
      for (int nb = 0; nb < 4; ++nb) {
        f32x4 s0 = {}, s1 = {};
#pragma unroll
        for (int c = 0; c < 4; ++c) {
          short8 kf = *(const short8*)&Ks[(nb * 16 + lr) * 128 + (((c * 4 + g) ^ x7) << 3)];
          s0 = __builtin_amdgcn_mfma_f32_16x16x32_bf16(kf, qf[0][c], s0, 0, 0, 0);
          s1 = __builtin_amdgcn_mfma_f32_16x16x32_bf16(kf, qf[1][c], s1, 0, 0, 0);
        }
        sc[0][nb] = s0;
        sc[1][nb] = s1;
      }
      __builtin_amdgcn_s_setprio(0);
    }

    if (t + 1 < ntiles) issue((t + 1) * 64);

    if (active) {
      const bool domask = (64 * t + 63 > qw);
#pragma unroll
      for (int qs = 0; qs < 2; ++qs) {
        const int qg = qw + qs * 16 + lr;
        float mnb[4];
#pragma unroll
        for (int nb = 0; nb < 4; ++nb) {
          if (domask) {
#pragma unroll
            for (int r = 0; r < 4; ++r) {
              int kv = t * 64 + nb * 16 + rowl + r;
              if (kv > qg) sc[qs][nb][r] = -1e30f;
            }
          }
          mnb[nb] = fmaxf(fmaxf(sc[qs][nb][0], sc[qs][nb][1]),
                          fmaxf(sc[qs][nb][2], sc[qs][nb][3]));
        }
        float mt = fmaxf(fmaxf(mnb[0], mnb[1]), fmaxf(mnb[2], mnb[3]));
        mt = fmaxf(mt, __shfl_xor(mt, 16));
        mt = fmaxf(mt, __shfl_xor(mt, 32));

        // T13 defer-max: only rescale when tile max exceeds running max + 8
        if (!__all(mt <= mrun[qs] + 8.f)) {
          float mnew = fmaxf(mrun[qs], mt);
          float alpha = exp2s(mrun[qs] - mnew);
          mrun[qs] = mnew;
          lrun[qs] *= alpha;
          float al[4];
#pragma unroll
          for (int r = 0; r < 4; ++r) al[r] = __shfl(alpha, (lane & 48) | (rowl + r));
#pragma unroll
          for (int f = 0; f < 8; ++f)
#pragma unroll
            for (int r = 0; r < 4; ++r) o[qs][f][r] *= al[r];
        }
        const float mcur = mrun[qs];

        float lsnb[4];
#pragma unroll
        for (int nb = 0; nb < 4; ++nb) {
          float p0 = exp2s(sc[qs][nb][0] - mcur);
          float p1 = exp2s(sc[qs][nb][1] - mcur);
          float p2 = exp2s(sc[qs][nb][2] - mcur);
          float p3 = exp2s(sc[qs][nb][3] - mcur);
          lsnb[nb] = (p0 + p1) + (p2 + p3);
          uint2 w;
          w.x = pack2(p0, p1);
          w.y = pack2(p2, p3);
          *(uint2*)&Ps[wid][qs * 16 + lr][nb * 16 + rowl] = w;
        }
        float ls = (lsnb[0] + lsnb[1]) + (lsnb[2] + lsnb[3]);
        ls += __shfl_xor(ls, 16);
        ls += __shfl_xor(ls, 32);
        lrun[qs] += ls;
      }

      asm volatile("s_waitcnt lgkmcnt(0)" ::: "memory");
      __builtin_amdgcn_sched_barrier(0);

      __builtin_amdgcn_s_setprio(1);
#pragma unroll
      for (int kc = 0; kc < 2; ++kc) {
        short8 pf0 = *(const short8*)&Ps[wid][lr][kc * 32 + lk];
        short8 pf1 = *(const short8*)&Ps[wid][16 + lr][kc * 32 + lk];
#pragma unroll
        for (int nb = 0; nb < 8; ++nb) {
          short8 vf = *(const short8*)&Vs[(nb * 16 + lr) * 64 + (((kc * 4 + g) ^ x7) << 3)];
          o[0][nb] = __builtin_amdgcn_mfma_f32_16x16x32_bf16(pf0, vf, o[0][nb], 0, 0, 0);
          o[1][nb] = __builtin_amdgcn_mfma_f32_16x16x32_bf16(pf1, vf, o[1][nb], 0, 0, 0);
        }
      }
      __builtin_amdgcn_s_setprio(0);
    }

    __syncthreads();
    if (t + 1 < ntiles) commit();
    __syncthreads();
  }

#pragma unroll
  for (int qs = 0; qs < 2; ++qs) {
    float ld[4];
#pragma unroll
    for (int r = 0; r < 4; ++r) ld[r] = __shfl(lrun[qs], (lane & 48) | (rowl + r));
#pragma unroll
    for (int f = 0; f < 8; ++f)
#pragma unroll
      for (int r = 0; r < 4; ++r) {
        float v = o[qs][f][r] / ld[r];
        attn[headq + (size_t)(qw + qs * 16 + rowl + r) * Dc + f * 16 + lr] = f2bf(v);
      }
  }
}

// ---------------------------------------------------------------------------
extern "C" void kernel_launch(void* const* d_in, const int* in_sizes, int n_in,
                              void* d_out, int out_size, void* d_ws, size_t ws_size,
                              hipStream_t stream) {
  const float* Q = (const float*)d_in[0];
  const float* K = (const float*)d_in[1];
  const float* V = (const float*)d_in[2];
  // d_in[3] = mask (causal tril, structural — unused)
  const float* wq = (const float*)d_in[4];
  const float* bq = (const float*)d_in[5];
  const float* wk = (const float*)d_in[6];
  const float* bk = (const float*)d_in[7];
  const float* wv = (const float*)d_in[8];
  const float* bv = (const float*)d_in[9];
  const float* wo = (const float*)d_in[10];
  const float* bo = (const float*)d_in[11];

  char* ws = (char*)d_ws;
  const size_t WSZ = (size_t)Dc * Dc;
  const size_t XSZ = (size_t)Bc * Sc * Dc;
  short* WT = (short*)ws;
  short* QP = (short*)(ws + 4 * WSZ * 2);
  short* KP = (short*)(ws + 4 * WSZ * 2 + XSZ * 2);
  short* VT = (short*)(ws + 4 * WSZ * 2 + 2 * XSZ * 2);
  short* AT = (short*)(ws + 4 * WSZ * 2 + 3 * XSZ * 2);  // conv scratch + attn out
  // total: 8*WSZ + 8*XSZ bytes = 32 MiB + 128 MiB = 160 MiB

  transpose_w_kernel<<<dim3(Dc / 32, Dc / 32, 4), 256, 0, stream>>>(wq, wk, wv, wo, WT);

  const int n8 = (int)(XSZ / 8);
  const int ng = (Bc * Sc / 256) * (Dc / 256);  // 256 blocks

  convert_kernel<<<2048, 256, 0, stream>>>(Q, AT, n8);
  gemm_ring_kernel<0><<<ng, 512, 0, stream>>>(AT, WT, bq, QP, SCALE2);
  convert_kernel<<<2048, 256, 0, stream>>>(K, AT, n8);
  gemm_ring_kernel<0><<<ng, 512, 0, stream>>>(AT, WT + WSZ, bk, KP, 1.f);
  convert_kernel<<<2048, 256, 0, stream>>>(V, AT, n8);
  gemm_ring_kernel<2><<<ng, 512, 0, stream>>>(AT, WT + 2 * WSZ, bv, VT, 1.f);

  attn_kernel<<<512, 512, 0, stream>>>(QP, KP, VT, AT);

  gemm_ring_kernel<1><<<ng, 512, 0, stream>>>(AT, WT + 3 * WSZ, bo, (float*)d_out, 1.f);
}

// Round 13
// 455.188 us; speedup vs baseline: 1.0840x; 1.0338x over previous
//
#include <hip/hip_runtime.h>
#include <hip/hip_bf16.h>

typedef __attribute__((ext_vector_type(8))) short short8;
typedef __attribute__((ext_vector_type(4))) float f32x4;

#define DEVINL __device__ __forceinline__

constexpr int Bc = 4, Sc = 2048, Dc = 2048, Hc = 16, DHc = 128;
// softmax in exp2 space: Q pre-scaled by 1/sqrt(128) * log2(e) in its GEMM
constexpr float SCALE2 = 0.08838834764831845f * 1.4426950408889634f;

DEVINL float exp2s(float x) { return __builtin_amdgcn_exp2f(x); }

DEVINL short f2bf(float f) {
  unsigned u = __builtin_bit_cast(unsigned, f);
  u = (u + 0x7fffu + ((u >> 16) & 1u)) >> 16;
  return (short)u;
}
DEVINL short bfc(float f) {
  __hip_bfloat16 h = __float2bfloat16(f);
  return __builtin_bit_cast(short, h);
}
DEVINL unsigned pack2(float a, float b) {
  return (unsigned)(unsigned short)f2bf(a) | ((unsigned)(unsigned short)f2bf(b) << 16);
}

// async global->LDS, 16B per lane; LDS dest = wave-uniform base + lane*16
DEVINL void gload16(const void* g, void* l) {
  __builtin_amdgcn_global_load_lds(
      (const __attribute__((address_space(1))) void*)g,
      (__attribute__((address_space(3))) void*)l, 16, 0, 0);
}

// ---------------- weight transpose + fp32->bf16:  wt[n][k] = w[k][n] -------
__global__ __launch_bounds__(256) void transpose_w_kernel(
    const float* __restrict__ w0, const float* __restrict__ w1,
    const float* __restrict__ w2, const float* __restrict__ w3,
    short* __restrict__ wt) {
  __shared__ float tile[32][33];
  const float* w = (blockIdx.z == 0) ? w0 : (blockIdx.z == 1) ? w1
                   : (blockIdx.z == 2) ? w2 : w3;
  short* out = wt + (size_t)blockIdx.z * Dc * Dc;
  int k0 = blockIdx.x * 32, n0 = blockIdx.y * 32;
  int t = threadIdx.x;
#pragma unroll
  for (int p = 0; p < 4; ++p) {
    int idx = p * 256 + t;
    int kr = idx >> 5, nc = idx & 31;
    tile[kr][nc] = w[(size_t)(k0 + kr) * Dc + n0 + nc];
  }
  __syncthreads();
#pragma unroll
  for (int p = 0; p < 4; ++p) {
    int idx = p * 256 + t;
    int nr = idx >> 5, kc = idx & 31;
    out[(size_t)(n0 + nr) * Dc + k0 + kc] = f2bf(tile[kc][nr]);
  }
}

// ---------------- 256x256 ring GEMM, A = f32 via global_load_lds -----------
// C = A_f32[M,K] @ Wt[N,K]^T + bias, scaled by oscale. Eliminates the
// separate f32->bf16 convert pass: A staged RAW f32 (3-slot ring, 96 KB),
// converted to bf16 at fragment read (2x ds_read_b128 + cvt_pk per frag).
// B bf16 3-slot ring (48 KB). slot = kt%3; stage(kt+2) at kt writes slot
// (kt-1)%3 whose reads are barrier-ordered complete (round-9 proof).
// 6 loads/kt (A4+B2): steady vmcnt(6) proves stage(kt); vmcnt(0) at kt=63.
// A LDS swizzle: 16B slot s at row r (128B rows) stored at s ^ (r&7).
// B LDS swizzle: as round-9 (s ^ ((r>>1)&3) on 64B rows).
// OUT_MODE: 0 = bf16 [M,N] (scaled), 2 = bf16 V-transposed [B,H,DH,S]
template <int OUT_MODE>
__global__ __launch_bounds__(512, 1) void gemm_ring_f32_kernel(
    const float* __restrict__ A, const short* __restrict__ Wt,
    const float* __restrict__ bias, void* __restrict__ Cptr, float oscale) {
  __shared__ __align__(16) float As[3][256 * 32];
  __shared__ __align__(16) short Bs[3][256 * 32];
  const int tid = threadIdx.x, lane = tid & 63, wid = tid >> 6;
  const int wm = wid >> 2, wn = wid & 3;
  const int lr = lane & 15, g = lane >> 4;
  const int physg = (g ^ ((lr >> 1) & 3)) * 8;  // B swizzled read col (shorts)

  // XCD-aware bijective swizzle: 256 blocks, 8 XCDs, 32 per XCD
  const int bid = blockIdx.x;
  const int swz = (bid & 7) * 32 + (bid >> 3);
  const int m0 = (swz >> 3) * 256, n0 = (swz & 7) * 256;

  // A staging: 4 gloads/kt, each 8 rows of 128B; phys slot = lane&7
  const int arow8 = lane >> 3, aslot = lane & 7;
  auto stageA = [&](int kt) {
    char* slotbase = (char*)&As[kt % 3][0];
#pragma unroll
    for (int p = 0; p < 4; ++p) {
      int row = wid * 32 + p * 8 + arow8;
      int col = (aslot ^ (row & 7)) * 4;  // pre-swizzled source col (f32)
      gload16(&A[(size_t)(m0 + row) * Dc + kt * 32 + col],
              slotbase + (wid * 32 + p * 8) * 128);
    }
  };

  // B staging: 2 gloads/kt (round-9 geometry)
  const int bsrow = lane >> 2;
  const int bscol = ((lane & 3) ^ ((lane >> 3) & 3)) * 8;
  const size_t bbase = (size_t)(n0 + wid * 32 + bsrow) * Dc + bscol;
  auto stageB = [&](int kt) {
    const short* src = &Wt[bbase + kt * 32];
    char* dst = (char*)&Bs[kt % 3][0] + wid * 32 * 64;
    gload16(src, dst);
    gload16(src + (size_t)16 * Dc, dst + 16 * 64);
  };

  // A fragment read: row-major [256][32] f32, slot-swizzled; cvt to bf16
  auto rdA = [&](const float* Ab, int row) -> short8 {
    const int r7 = row & 7;
    const char* rb = (const char*)(Ab + row * 32);
    f32x4 a0 = *(const f32x4*)(rb + (((2 * g) ^ r7) * 16));
    f32x4 a1 = *(const f32x4*)(rb + (((2 * g + 1) ^ r7) * 16));
    short8 r;
    r[0] = bfc(a0[0]); r[1] = bfc(a0[1]); r[2] = bfc(a0[2]); r[3] = bfc(a0[3]);
    r[4] = bfc(a1[0]); r[5] = bfc(a1[1]); r[6] = bfc(a1[2]); r[7] = bfc(a1[3]);
    return r;
  };

  f32x4 acc[8][4] = {};

  stageA(0); stageB(0);
  stageA(1); stageB(1);

  for (int kt = 0; kt < 64; ++kt) {
    // counted wait: own stage(kt) done; barrier => ALL waves' stage(kt) done.
    if (kt < 63) {
      asm volatile("s_waitcnt vmcnt(6)" ::: "memory");
    } else {
      asm volatile("s_waitcnt vmcnt(0)" ::: "memory");
    }
    __builtin_amdgcn_s_barrier();
    asm volatile("" ::: "memory");  // reads may not hoist above the barrier

    const float* Ab = &As[kt % 3][0];
    const short* Bb = &Bs[kt % 3][0];
    short8 afr[4], bfr[4], af2[4];
#pragma unroll
    for (int i = 0; i < 4; ++i) afr[i] = rdA(Ab, wm * 128 + i * 16 + lr);
#pragma unroll
    for (int j = 0; j < 4; ++j)
      bfr[j] = *(const short8*)&Bb[(wn * 64 + j * 16 + lr) * 32 + physg];
#pragma unroll
    for (int i = 0; i < 4; ++i) af2[i] = rdA(Ab, wm * 128 + 64 + i * 16 + lr);

    if (kt <= 61) { stageA(kt + 2); stageB(kt + 2); }  // writes slot (kt-1)%3

    __builtin_amdgcn_s_setprio(1);
#pragma unroll
    for (int i = 0; i < 4; ++i)
#pragma unroll
      for (int j = 0; j < 4; ++j)
        acc[i][j] = __builtin_amdgcn_mfma_f32_16x16x32_bf16(afr[i], bfr[j], acc[i][j], 0, 0, 0);
#pragma unroll
    for (int i = 0; i < 4; ++i)
#pragma unroll
      for (int j = 0; j < 4; ++j)
        acc[4 + i][j] = __builtin_amdgcn_mfma_f32_16x16x32_bf16(af2[i], bfr[j], acc[4 + i][j], 0, 0, 0);
    __builtin_amdgcn_s_setprio(0);
  }

  const int rowl = g * 4;
#pragma unroll
  for (int bj = 0; bj < 4; ++bj) {
    const int gcol = n0 + wn * 64 + bj * 16 + lr;
    const float bv = bias[gcol];
#pragma unroll
    for (int ai = 0; ai < 8; ++ai) {
#pragma unroll
      for (int r = 0; r < 4; ++r) {
        int grow = m0 + wm * 128 + ai * 16 + rowl + r;
        float v = (acc[ai][bj][r] + bv) * oscale;
        if (OUT_MODE == 0) {
          ((short*)Cptr)[(size_t)grow * Dc + gcol] = f2bf(v);
        } else {
          int b4 = grow >> 11, ss = grow & (Sc - 1);
          int hh = gcol >> 7, dh = gcol & (DHc - 1);
          ((short*)Cptr)[((((size_t)(b4 * Hc + hh) * DHc) + dh) << 11) + ss] = f2bf(v);
        }
      }
    }
  }
}

// ---------------- 256x256 ring GEMM, A = bf16 (round-9 proven) -------------
// OUT_MODE: 1 = f32 [M,N]
template <int OUT_MODE>
__global__ __launch_bounds__(512, 1) void gemm_ring_kernel(
    const short* __restrict__ A, const short* __restrict__ Wt,
    const float* __restrict__ bias, void* __restrict__ Cptr, float oscale) {
  __shared__ __align__(16) short As[4][256 * 32];
  __shared__ __align__(16) short Bs[4][256 * 32];
  const int tid = threadIdx.x, lane = tid & 63, wid = tid >> 6;
  const int wm = wid >> 2, wn = wid & 3;
  const int lr = lane & 15, g = lane >> 4;
  const int physg = (g ^ ((lr >> 1) & 3)) * 8;

  const int bid = blockIdx.x;
  const int swz = (bid & 7) * 32 + (bid >> 3);
  const int m0 = (swz >> 3) * 256, n0 = (swz & 7) * 256;

  const int srow = lane >> 2;
  const int scol = ((lane & 3) ^ ((lane >> 3) & 3)) * 8;
  const size_t abase = (size_t)(m0 + wid * 32 + srow) * Dc + scol;
  const size_t bbase = (size_t)(n0 + wid * 32 + srow) * Dc + scol;
  const int ldof = wid * 32 * 64;

  auto stageA = [&](int kt) {
    const short* src = &A[abase + kt * 32];
    char* dst = (char*)&As[kt & 3][0] + ldof;
    gload16(src, dst);
    gload16(src + (size_t)16 * Dc, dst + 16 * 64);
  };
  auto stageB = [&](int kt) {
    const short* src = &Wt[bbase + kt * 32];
    char* dst = (char*)&Bs[kt & 3][0] + ldof;
    gload16(src, dst);
    gload16(src + (size_t)16 * Dc, dst + 16 * 64);
  };

  f32x4 acc[8][4] = {};

  stageA(0); stageB(0);
  stageA(1); stageB(1);
  stageA(2); stageB(2);

  for (int kt = 0; kt < 64; ++kt) {
    if (kt < 62) {
      asm volatile("s_waitcnt vmcnt(8)" ::: "memory");
    } else if (kt == 62) {
      asm volatile("s_waitcnt vmcnt(4)" ::: "memory");
    } else {
      asm volatile("s_waitcnt vmcnt(0)" ::: "memory");
    }
    __builtin_amdgcn_s_barrier();
    asm volatile("" ::: "memory");

    const short* Ab = &As[kt & 3][0];
    const short* Bb = &Bs[kt & 3][0];
    short8 afr[4], bfr[4], af2[4];
#pragma unroll
    for (int i = 0; i < 4; ++i)
      afr[i] = *(const short8*)&Ab[(wm * 128 + i * 16 + lr) * 32 + physg];
#pragma unroll
    for (int j = 0; j < 4; ++j)
      bfr[j] = *(const short8*)&Bb[(wn * 64 + j * 16 + lr) * 32 + physg];
#pragma unroll
    for (int i = 0; i < 4; ++i)
      af2[i] = *(const short8*)&Ab[(wm * 128 + 64 + i * 16 + lr) * 32 + physg];

    if (kt <= 60) { stageA(kt + 3); stageB(kt + 3); }

    __builtin_amdgcn_s_setprio(1);
#pragma unroll
    for (int i = 0; i < 4; ++i)
#pragma unroll
      for (int j = 0; j < 4; ++j)
        acc[i][j] = __builtin_amdgcn_mfma_f32_16x16x32_bf16(afr[i], bfr[j], acc[i][j], 0, 0, 0);
#pragma unroll
    for (int i = 0; i < 4; ++i)
#pragma unroll
      for (int j = 0; j < 4; ++j)
        acc[4 + i][j] = __builtin_amdgcn_mfma_f32_16x16x32_bf16(af2[i], bfr[j], acc[4 + i][j], 0, 0, 0);
    __builtin_amdgcn_s_setprio(0);
  }

  const int rowl = g * 4;
#pragma unroll
  for (int bj = 0; bj < 4; ++bj) {
    const int gcol = n0 + wn * 64 + bj * 16 + lr;
    const float bv = bias[gcol];
#pragma unroll
    for (int ai = 0; ai < 8; ++ai) {
#pragma unroll
      for (int r = 0; r < 4; ++r) {
        int grow = m0 + wm * 128 + ai * 16 + rowl + r;
        float v = (acc[ai][bj][r] + bv) * oscale;
        ((float*)Cptr)[(size_t)grow * Dc + gcol] = v;
      }
    }
  }
}

// ---------------- flash attention (causal), QB=256, 8 waves ----------------
// Swapped QK^T (lane owns q-rows) + T14 reg-staging + T13 defer-max.
// Q pre-scaled by SCALE2 in its projection -> scores already in log2 space.
// LDS XOR-swizzled 16B slots: Ks[row][s^=(row&7)], Vs[d][s^=(d&7)].
__global__ __launch_bounds__(512, 2) void attn_kernel(
    const short* __restrict__ qp, const short* __restrict__ kp,
    const short* __restrict__ vt, short* __restrict__ attn) {
  __shared__ __align__(16) short Ks[64 * 128];
  __shared__ __align__(16) short Vs[128 * 64];
  __shared__ __align__(16) short Ps[8][32][72];
  const int tid = threadIdx.x, lane = tid & 63, wid = tid >> 6;
  const int lr = lane & 15, g = lane >> 4, lk = g * 8, rowl = g * 4;
  const int d = blockIdx.x;
  const int xcd = d & 7, s = d >> 3;
  const int grp = s >> 3;
  const int qi = (grp < 4) ? grp : 11 - grp;  // 0,1,2,3,7,6,5,4
  const int bh = xcd * 8 + (s & 7);
  const int b = bh >> 4, h = bh & 15;
  const int qb = qi * 256;
  const size_t headq = ((size_t)b * Sc) * Dc + (size_t)h * DHc;
  const size_t vbase = (((size_t)b * Hc + h) * DHc) << 11;
  const int qw = qb + wid * 32;
  const int x7 = lr & 7;

  short8 qf[2][4];
#pragma unroll
  for (int qs = 0; qs < 2; ++qs)
#pragma unroll
    for (int c = 0; c < 4; ++c)
      qf[qs][c] = *(const short8*)&qp[headq + (size_t)(qw + qs * 16 + lr) * Dc + c * 32 + lk];

  const int krow = wid * 4 + g;
  const int kcol = lr * 8;
  const int vrow = wid * 8 + (lane >> 3);
  const int vcol = (lane & 7) * 8;
  int kdst[2], vdst[2];
#pragma unroll
  for (int p = 0; p < 2; ++p) {
    int kr = p * 32 + krow;
    kdst[p] = kr * 128 + ((lr ^ (kr & 7)) * 8);
    int vr = p * 64 + vrow;
    vdst[p] = vr * 64 + (((lane & 7) ^ (vr & 7)) * 8);
  }

  short8 kreg[2], vreg[2];
  auto issue = [&](int kvb) {
#pragma unroll
    for (int p = 0; p < 2; ++p)
      kreg[p] = *(const short8*)&kp[headq + (size_t)(kvb + p * 32 + krow) * Dc + kcol];
#pragma unroll
    for (int p = 0; p < 2; ++p)
      vreg[p] = *(const short8*)&vt[vbase + (size_t)(p * 64 + vrow) * Sc + kvb + vcol];
  };
  auto commit = [&]() {
#pragma unroll
    for (int p = 0; p < 2; ++p) *(short8*)&Ks[kdst[p]] = kreg[p];
#pragma unroll
    for (int p = 0; p < 2; ++p) *(short8*)&Vs[vdst[p]] = vreg[p];
  };

  issue(0);
  commit();
  __syncthreads();

  f32x4 o[2][8] = {};
  float mrun[2] = {-1e30f, -1e30f}, lrun[2] = {0.f, 0.f};
  const int ntiles = qb / 64 + 4;

  for (int t = 0; t < ntiles; ++t) {
    const bool active = (64 * t <= qw + 31);  // wave-uniform
    f32x4 sc[2][4];

    if (active) {
      __builtin_amdgcn_s_setprio(1);
#pragma unroll
      for (int nb = 0; nb < 4; ++nb) {
        f32x4 s0 = {}, s1 = {};
#pragma unroll
        for (int c = 0; c < 4; ++c) {
          short8 kf = *(const short8*)&Ks[(nb * 16 + lr) * 128 + (((c * 4 + g) ^ x7) << 3)];
          s0 = __builtin_amdgcn_mfma_f32_16x16x32_bf16(kf, qf[0][c], s0, 0, 0, 0);
          s1 = __builtin_amdgcn_mfma_f32_16x16x32_bf16(kf, qf[1][c], s1, 0, 0, 0);
        }
        sc[0][nb] = s0;
        sc[1][nb] = s1;
      }
      __builtin_amdgcn_s_setprio(0);
    }

    if (t + 1 < ntiles) issue((t + 1) * 64);

    if (active) {
      const bool domask = (64 * t + 63 > qw);
#pragma unroll
      for (int qs = 0; qs < 2; ++qs) {
        const int qg = qw + qs * 16 + lr;
        float mnb[4];
#pragma unroll
        for (int nb = 0; nb < 4; ++nb) {
          if (domask) {
#pragma unroll
            for (int r = 0; r < 4; ++r) {
              int kv = t * 64 + nb * 16 + rowl + r;
              if (kv > qg) sc[qs][nb][r] = -1e30f;
            }
          }
          mnb[nb] = fmaxf(fmaxf(sc[qs][nb][0], sc[qs][nb][1]),
                          fmaxf(sc[qs][nb][2], sc[qs][nb][3]));
        }
        float mt = fmaxf(fmaxf(mnb[0], mnb[1]), fmaxf(mnb[2], mnb[3]));
        mt = fmaxf(mt, __shfl_xor(mt, 16));
        mt = fmaxf(mt, __shfl_xor(mt, 32));

        // T13 defer-max: only rescale when tile max exceeds running max + 8
        if (!__all(mt <= mrun[qs] + 8.f)) {
          float mnew = fmaxf(mrun[qs], mt);
          float alpha = exp2s(mrun[qs] - mnew);
          mrun[qs] = mnew;
          lrun[qs] *= alpha;
          float al[4];
#pragma unroll
          for (int r = 0; r < 4; ++r) al[r] = __shfl(alpha, (lane & 48) | (rowl + r));
#pragma unroll
          for (int f = 0; f < 8; ++f)
#pragma unroll
            for (int r = 0; r < 4; ++r) o[qs][f][r] *= al[r];
        }
        const float mcur = mrun[qs];

        float lsnb[4];
#pragma unroll
        for (int nb = 0; nb < 4; ++nb) {
          float p0 = exp2s(sc[qs][nb][0] - mcur);
          float p1 = exp2s(sc[qs][nb][1] - mcur);
          float p2 = exp2s(sc[qs][nb][2] - mcur);
          float p3 = exp2s(sc[qs][nb][3] - mcur);
          lsnb[nb] = (p0 + p1) + (p2 + p3);
          uint2 w;
          w.x = pack2(p0, p1);
          w.y = pack2(p2, p3);
          *(uint2*)&Ps[wid][qs * 16 + lr][nb * 16 + rowl] = w;
        }
        float ls = (lsnb[0] + lsnb[1]) + (lsnb[2] + lsnb[3]);
        ls += __shfl_xor(ls, 16);
        ls += __shfl_xor(ls, 32);
        lrun[qs] += ls;
      }

      asm volatile("s_waitcnt lgkmcnt(0)" ::: "memory");
      __builtin_amdgcn_sched_barrier(0);

      __builtin_amdgcn_s_setprio(1);
#pragma unroll
      for (int kc = 0; kc < 2; ++kc) {
        short8 pf0 = *(const short8*)&Ps[wid][lr][kc * 32 + lk];
        short8 pf1 = *(const short8*)&Ps[wid][16 + lr][kc * 32 + lk];
#pragma unroll
        for (int nb = 0; nb < 8; ++nb) {
          short8 vf = *(const short8*)&Vs[(nb * 16 + lr) * 64 + (((kc * 4 + g) ^ x7) << 3)];
          o[0][nb] = __builtin_amdgcn_mfma_f32_16x16x32_bf16(pf0, vf, o[0][nb], 0, 0, 0);
          o[1][nb] = __builtin_amdgcn_mfma_f32_16x16x32_bf16(pf1, vf, o[1][nb], 0, 0, 0);
        }
      }
      __builtin_amdgcn_s_setprio(0);
    }

    __syncthreads();
    if (t + 1 < ntiles) commit();
    __syncthreads();
  }

#pragma unroll
  for (int qs = 0; qs < 2; ++qs) {
    float ld[4];
#pragma unroll
    for (int r = 0; r < 4; ++r) ld[r] = __shfl(lrun[qs], (lane & 48) | (rowl + r));
#pragma unroll
    for (int f = 0; f < 8; ++f)
#pragma unroll
      for (int r = 0; r < 4; ++r) {
        float v = o[qs][f][r] / ld[r];
        attn[headq + (size_t)(qw + qs * 16 + rowl + r) * Dc + f * 16 + lr] = f2bf(v);
      }
  }
}

// ---------------------------------------------------------------------------
extern "C" void kernel_launch(void* const* d_in, const int* in_sizes, int n_in,
                              void* d_out, int out_size, void* d_ws, size_t ws_size,
                              hipStream_t stream) {
  const float* Q = (const float*)d_in[0];
  const float* K = (const float*)d_in[1];
  const float* V = (const float*)d_in[2];
  // d_in[3] = mask (causal tril, structural — unused)
  const float* wq = (const float*)d_in[4];
  const float* bq = (const float*)d_in[5];
  const float* wk = (const float*)d_in[6];
  const float* bk = (const float*)d_in[7];
  const float* wv = (const float*)d_in[8];
  const float* bv = (const float*)d_in[9];
  const float* wo = (const float*)d_in[10];
  const float* bo = (const float*)d_in[11];

  char* ws = (char*)d_ws;
  const size_t WSZ = (size_t)Dc * Dc;
  const size_t XSZ = (size_t)Bc * Sc * Dc;
  short* WT = (short*)ws;
  short* QP = (short*)(ws + 4 * WSZ * 2);
  short* KP = (short*)(ws + 4 * WSZ * 2 + XSZ * 2);
  short* VT = (short*)(ws + 4 * WSZ * 2 + 2 * XSZ * 2);
  short* AT = (short*)(ws + 4 * WSZ * 2 + 3 * XSZ * 2);  // attn out
  // total: 8*WSZ + 8*XSZ bytes = 32 MiB + 128 MiB = 160 MiB

  transpose_w_kernel<<<dim3(Dc / 32, Dc / 32, 4), 256, 0, stream>>>(wq, wk, wv, wo, WT);

  const int ng = (Bc * Sc / 256) * (Dc / 256);  // 256 blocks

  gemm_ring_f32_kernel<0><<<ng, 512, 0, stream>>>(Q, WT, bq, QP, SCALE2);
  gemm_ring_f32_kernel<0><<<ng, 512, 0, stream>>>(K, WT + WSZ, bk, KP, 1.f);
  gemm_ring_f32_kernel<2><<<ng, 512, 0, stream>>>(V, WT + 2 * WSZ, bv, VT, 1.f);

  attn_kernel<<<512, 512, 0, stream>>>(QP, KP, VT, AT);

  gemm_ring_kernel<1><<<ng, 512, 0, stream>>>(AT, WT + 3 * WSZ, bo, (float*)d_out, 1.f);
}

// Round 14
// 454.630 us; speedup vs baseline: 1.0853x; 1.0012x over previous
//
#include <hip/hip_runtime.h>
#include <hip/hip_bf16.h>

typedef __attribute__((ext_vector_type(8))) short short8;
typedef __attribute__((ext_vector_type(4))) float f32x4;

#define DEVINL __device__ __forceinline__

constexpr int Bc = 4, Sc = 2048, Dc = 2048, Hc = 16, DHc = 128;
// softmax in exp2 space: Q pre-scaled by 1/sqrt(128) * log2(e) in its GEMM
constexpr float SCALE2 = 0.08838834764831845f * 1.4426950408889634f;

DEVINL float exp2s(float x) { return __builtin_amdgcn_exp2f(x); }

DEVINL short f2bf(float f) {
  unsigned u = __builtin_bit_cast(unsigned, f);
  u = (u + 0x7fffu + ((u >> 16) & 1u)) >> 16;
  return (short)u;
}
DEVINL short bfc(float f) {
  __hip_bfloat16 h = __float2bfloat16(f);
  return __builtin_bit_cast(short, h);
}
DEVINL unsigned pack2(float a, float b) {
  return (unsigned)(unsigned short)f2bf(a) | ((unsigned)(unsigned short)f2bf(b) << 16);
}

// async global->LDS, 16B per lane; LDS dest = wave-uniform base + lane*16
DEVINL void gload16(const void* g, void* l) {
  __builtin_amdgcn_global_load_lds(
      (const __attribute__((address_space(1))) void*)g,
      (__attribute__((address_space(3))) void*)l, 16, 0, 0);
}

// ---------------- weight transpose + fp32->bf16:  wt[n][k] = w[k][n] -------
__global__ __launch_bounds__(256) void transpose_w_kernel(
    const float* __restrict__ w0, const float* __restrict__ w1,
    const float* __restrict__ w2, const float* __restrict__ w3,
    short* __restrict__ wt) {
  __shared__ float tile[32][33];
  const float* w = (blockIdx.z == 0) ? w0 : (blockIdx.z == 1) ? w1
                   : (blockIdx.z == 2) ? w2 : w3;
  short* out = wt + (size_t)blockIdx.z * Dc * Dc;
  int k0 = blockIdx.x * 32, n0 = blockIdx.y * 32;
  int t = threadIdx.x;
#pragma unroll
  for (int p = 0; p < 4; ++p) {
    int idx = p * 256 + t;
    int kr = idx >> 5, nc = idx & 31;
    tile[kr][nc] = w[(size_t)(k0 + kr) * Dc + n0 + nc];
  }
  __syncthreads();
#pragma unroll
  for (int p = 0; p < 4; ++p) {
    int idx = p * 256 + t;
    int nr = idx >> 5, kc = idx & 31;
    out[(size_t)(n0 + nr) * Dc + k0 + kc] = f2bf(tile[kc][nr]);
  }
}

// ---------------- merged QKV GEMM, A = f32 via global_load_lds -------------
// One 768-block dispatch = 3 x 256-block GEMMs (t = bid>>8 selects tensor):
// eliminates 2 kernel-boundary drains; fast CUs start the next tensor early.
// C = A_f32[M,K] @ Wt[N,K]^T + bias, scaled by oscale (Q gets SCALE2).
// A staged RAW f32 (3-slot ring, 96 KB), cvt to bf16 at fragment read.
// B bf16 3-slot ring (48 KB). slot = kt%3; stage(kt+2) at kt writes slot
// (kt-1)%3 whose reads are barrier-ordered complete (round-9 proof).
// 6 loads/kt: steady vmcnt(6) proves stage(kt); vmcnt(0) at kt=63 only.
// A LDS swizzle: 16B slot s at row r (128B rows) stored at s ^ (r&7).
// B LDS swizzle: s ^ ((r>>1)&3) on 64B rows.
// mode: 0 = bf16 [M,N] (scaled), 2 = bf16 V-transposed [B,H,DH,S]
__global__ __launch_bounds__(512, 1) void qkv_gemm_kernel(
    const float* __restrict__ Qin, const float* __restrict__ Kin,
    const float* __restrict__ Vin, const short* __restrict__ WTbase,
    const float* __restrict__ bq, const float* __restrict__ bk,
    const float* __restrict__ bv, short* __restrict__ QP,
    short* __restrict__ KP, short* __restrict__ VT) {
  __shared__ __align__(16) float As[3][256 * 32];
  __shared__ __align__(16) short Bs[3][256 * 32];
  const int tid = threadIdx.x, lane = tid & 63, wid = tid >> 6;
  const int wm = wid >> 2, wn = wid & 3;
  const int lr = lane & 15, g = lane >> 4;
  const int physg = (g ^ ((lr >> 1) & 3)) * 8;  // B swizzled read col (shorts)

  // tensor select
  const int tsel = blockIdx.x >> 8;
  const float* A = (tsel == 0) ? Qin : (tsel == 1) ? Kin : Vin;
  const short* Wt = WTbase + (size_t)tsel * Dc * Dc;
  const float* bias = (tsel == 0) ? bq : (tsel == 1) ? bk : bv;
  short* Cptr = (tsel == 0) ? QP : (tsel == 1) ? KP : VT;
  const float oscale = (tsel == 0) ? SCALE2 : 1.f;
  const int mode = (tsel == 2) ? 2 : 0;

  // XCD-aware bijective swizzle on local bid: 256 blocks, 8 XCDs, 32 per XCD
  const int bid = blockIdx.x & 255;  // (bid&7) == (blockIdx.x&7): XCD intact
  const int swz = (bid & 7) * 32 + (bid >> 3);
  const int m0 = (swz >> 3) * 256, n0 = (swz & 7) * 256;

  // A staging: 4 gloads/kt, each 8 rows of 128B; phys slot = lane&7
  const int arow8 = lane >> 3, aslot = lane & 7;
  auto stageA = [&](int kt) {
    char* slotbase = (char*)&As[kt % 3][0];
#pragma unroll
    for (int p = 0; p < 4; ++p) {
      int row = wid * 32 + p * 8 + arow8;
      int col = (aslot ^ (row & 7)) * 4;  // pre-swizzled source col (f32)
      gload16(&A[(size_t)(m0 + row) * Dc + kt * 32 + col],
              slotbase + (wid * 32 + p * 8) * 128);
    }
  };

  // B staging: 2 gloads/kt
  const int bsrow = lane >> 2;
  const int bscol = ((lane & 3) ^ ((lane >> 3) & 3)) * 8;
  const size_t bbase = (size_t)(n0 + wid * 32 + bsrow) * Dc + bscol;
  auto stageB = [&](int kt) {
    const short* src = &Wt[bbase + kt * 32];
    char* dst = (char*)&Bs[kt % 3][0] + wid * 32 * 64;
    gload16(src, dst);
    gload16(src + (size_t)16 * Dc, dst + 16 * 64);
  };

  // A fragment read: row-major [256][32] f32, slot-swizzled; cvt to bf16
  auto rdA = [&](const float* Ab, int row) -> short8 {
    const int r7 = row & 7;
    const char* rb = (const char*)(Ab + row * 32);
    f32x4 a0 = *(const f32x4*)(rb + (((2 * g) ^ r7) * 16));
    f32x4 a1 = *(const f32x4*)(rb + (((2 * g + 1) ^ r7) * 16));
    short8 r;
    r[0] = bfc(a0[0]); r[1] = bfc(a0[1]); r[2] = bfc(a0[2]); r[3] = bfc(a0[3]);
    r[4] = bfc(a1[0]); r[5] = bfc(a1[1]); r[6] = bfc(a1[2]); r[7] = bfc(a1[3]);
    return r;
  };

  f32x4 acc[8][4] = {};

  stageA(0); stageB(0);
  stageA(1); stageB(1);

  for (int kt = 0; kt < 64; ++kt) {
    // counted wait: own stage(kt) done; barrier => ALL waves' stage(kt) done.
    if (kt < 63) {
      asm volatile("s_waitcnt vmcnt(6)" ::: "memory");
    } else {
      asm volatile("s_waitcnt vmcnt(0)" ::: "memory");
    }
    __builtin_amdgcn_s_barrier();
    asm volatile("" ::: "memory");  // reads may not hoist above the barrier

    const float* Ab = &As[kt % 3][0];
    const short* Bb = &Bs[kt % 3][0];
    short8 afr[4], bfr[4], af2[4];
#pragma unroll
    for (int i = 0; i < 4; ++i) afr[i] = rdA(Ab, wm * 128 + i * 16 + lr);
#pragma unroll
    for (int j = 0; j < 4; ++j)
      bfr[j] = *(const short8*)&Bb[(wn * 64 + j * 16 + lr) * 32 + physg];
#pragma unroll
    for (int i = 0; i < 4; ++i) af2[i] = rdA(Ab, wm * 128 + 64 + i * 16 + lr);

    if (kt <= 61) { stageA(kt + 2); stageB(kt + 2); }  // writes slot (kt-1)%3

    __builtin_amdgcn_s_setprio(1);
#pragma unroll
    for (int i = 0; i < 4; ++i)
#pragma unroll
      for (int j = 0; j < 4; ++j)
        acc[i][j] = __builtin_amdgcn_mfma_f32_16x16x32_bf16(afr[i], bfr[j], acc[i][j], 0, 0, 0);
#pragma unroll
    for (int i = 0; i < 4; ++i)
#pragma unroll
      for (int j = 0; j < 4; ++j)
        acc[4 + i][j] = __builtin_amdgcn_mfma_f32_16x16x32_bf16(af2[i], bfr[j], acc[4 + i][j], 0, 0, 0);
    __builtin_amdgcn_s_setprio(0);
  }

  const int rowl = g * 4;
  if (mode == 0) {
#pragma unroll
    for (int bj = 0; bj < 4; ++bj) {
      const int gcol = n0 + wn * 64 + bj * 16 + lr;
      const float bv_ = bias[gcol];
#pragma unroll
      for (int ai = 0; ai < 8; ++ai)
#pragma unroll
        for (int r = 0; r < 4; ++r) {
          int grow = m0 + wm * 128 + ai * 16 + rowl + r;
          Cptr[(size_t)grow * Dc + gcol] = f2bf((acc[ai][bj][r] + bv_) * oscale);
        }
    }
  } else {
#pragma unroll
    for (int bj = 0; bj < 4; ++bj) {
      const int gcol = n0 + wn * 64 + bj * 16 + lr;
      const float bv_ = bias[gcol];
      const int hh = gcol >> 7, dh = gcol & (DHc - 1);
#pragma unroll
      for (int ai = 0; ai < 8; ++ai)
#pragma unroll
        for (int r = 0; r < 4; ++r) {
          int grow = m0 + wm * 128 + ai * 16 + rowl + r;
          int b4 = grow >> 11, ss = grow & (Sc - 1);
          Cptr[((((size_t)(b4 * Hc + hh) * DHc) + dh) << 11) + ss] =
              f2bf(acc[ai][bj][r] + bv_);
        }
    }
  }
}

// ---------------- 256x256 ring GEMM, A = bf16 (round-9 proven) -------------
// OUT_MODE: 1 = f32 [M,N]
template <int OUT_MODE>
__global__ __launch_bounds__(512, 1) void gemm_ring_kernel(
    const short* __restrict__ A, const short* __restrict__ Wt,
    const float* __restrict__ bias, void* __restrict__ Cptr, float oscale) {
  __shared__ __align__(16) short As[4][256 * 32];
  __shared__ __align__(16) short Bs[4][256 * 32];
  const int tid = threadIdx.x, lane = tid & 63, wid = tid >> 6;
  const int wm = wid >> 2, wn = wid & 3;
  const int lr = lane & 15, g = lane >> 4;
  const int physg = (g ^ ((lr >> 1) & 3)) * 8;

  const int bid = blockIdx.x;
  const int swz = (bid & 7) * 32 + (bid >> 3);
  const int m0 = (swz >> 3) * 256, n0 = (swz & 7) * 256;

  const int srow = lane >> 2;
  const int scol = ((lane & 3) ^ ((lane >> 3) & 3)) * 8;
  const size_t abase = (size_t)(m0 + wid * 32 + srow) * Dc + scol;
  const size_t bbase = (size_t)(n0 + wid * 32 + srow) * Dc + scol;
  const int ldof = wid * 32 * 64;

  auto stageA = [&](int kt) {
    const short* src = &A[abase + kt * 32];
    char* dst = (char*)&As[kt & 3][0] + ldof;
    gload16(src, dst);
    gload16(src + (size_t)16 * Dc, dst + 16 * 64);
  };
  auto stageB = [&](int kt) {
    const short* src = &Wt[bbase + kt * 32];
    char* dst = (char*)&Bs[kt & 3][0] + ldof;
    gload16(src, dst);
    gload16(src + (size_t)16 * Dc, dst + 16 * 64);
  };

  f32x4 acc[8][4] = {};

  stageA(0); stageB(0);
  stageA(1); stageB(1);
  stageA(2); stageB(2);

  for (int kt = 0; kt < 64; ++kt) {
    if (kt < 62) {
      asm volatile("s_waitcnt vmcnt(8)" ::: "memory");
    } else if (kt == 62) {
      asm volatile("s_waitcnt vmcnt(4)" ::: "memory");
    } else {
      asm volatile("s_waitcnt vmcnt(0)" ::: "memory");
    }
    __builtin_amdgcn_s_barrier();
    asm volatile("" ::: "memory");

    const short* Ab = &As[kt & 3][0];
    const short* Bb = &Bs[kt & 3][0];
    short8 afr[4], bfr[4], af2[4];
#pragma unroll
    for (int i = 0; i < 4; ++i)
      afr[i] = *(const short8*)&Ab[(wm * 128 + i * 16 + lr) * 32 + physg];
#pragma unroll
    for (int j = 0; j < 4; ++j)
      bfr[j] = *(const short8*)&Bb[(wn * 64 + j * 16 + lr) * 32 + physg];
#pragma unroll
    for (int i = 0; i < 4; ++i)
      af2[i] = *(const short8*)&Ab[(wm * 128 + 64 + i * 16 + lr) * 32 + physg];

    if (kt <= 60) { stageA(kt + 3); stageB(kt + 3); }

    __builtin_amdgcn_s_setprio(1);
#pragma unroll
    for (int i = 0; i < 4; ++i)
#pragma unroll
      for (int j = 0; j < 4; ++j)
        acc[i][j] = __builtin_amdgcn_mfma_f32_16x16x32_bf16(afr[i], bfr[j], acc[i][j], 0, 0, 0);
#pragma unroll
    for (int i = 0; i < 4; ++i)
#pragma unroll
      for (int j = 0; j < 4; ++j)
        acc[4 + i][j] = __builtin_amdgcn_mfma_f32_16x16x32_bf16(af2[i], bfr[j], acc[4 + i][j], 0, 0, 0);
    __builtin_amdgcn_s_setprio(0);
  }

  const int rowl = g * 4;
#pragma unroll
  for (int bj = 0; bj < 4; ++bj) {
    const int gcol = n0 + wn * 64 + bj * 16 + lr;
    const float bv = bias[gcol];
#pragma unroll
    for (int ai = 0; ai < 8; ++ai) {
#pragma unroll
      for (int r = 0; r < 4; ++r) {
        int grow = m0 + wm * 128 + ai * 16 + rowl + r;
        float v = (acc[ai][bj][r] + bv) * oscale;
        ((float*)Cptr)[(size_t)grow * Dc + gcol] = v;
      }
    }
  }
}

// ---------------- flash attention (causal), QB=256, 8 waves ----------------
// Swapped QK^T (lane owns q-rows) + T14 reg-staging + T13 defer-max.
// Q pre-scaled by SCALE2 in its projection -> scores already in log2 space.
// LDS XOR-swizzled 16B slots: Ks[row][s^=(row&7)], Vs[d][s^=(d&7)].
__global__ __launch_bounds__(512, 2) void attn_kernel(
    const short* __restrict__ qp, const short* __restrict__ kp,
    const short* __restrict__ vt, short* __restrict__ attn) {
  __shared__ __align__(16) short Ks[64 * 128];
  __shared__ __align__(16) short Vs[128 * 64];
  __shared__ __align__(16) short Ps[8][32][72];
  const int tid = threadIdx.x, lane = tid & 63, wid = tid >> 6;
  const int lr = lane & 15, g = lane >> 4, lk = g * 8, rowl = g * 4;
  const int d = blockIdx.x;
  const int xcd = d & 7, s = d >> 3;
  const int grp = s >> 3;
  const int qi = (grp < 4) ? grp : 11 - grp;  // 0,1,2,3,7,6,5,4
  const int bh = xcd * 8 + (s & 7);
  const int b = bh >> 4, h = bh & 15;
  const int qb = qi * 256;
  const size_t headq = ((size_t)b * Sc) * Dc + (size_t)h * DHc;
  const size_t vbase = (((size_t)b * Hc + h) * DHc) << 11;
  const int qw = qb + wid * 32;
  const int x7 = lr & 7;

  short8 qf[2][4];
#pragma unroll
  for (int qs = 0; qs < 2; ++qs)
#pragma unroll
    for (int c = 0; c < 4; ++c)
      qf[qs][c] = *(const short8*)&qp[headq + (size_t)(qw + qs * 16 + lr) * Dc + c * 32 + lk];

  const int krow = wid * 4 + g;
  const int kcol = lr * 8;
  const int vrow = wid * 8 + (lane >> 3);
  const int vcol = (lane & 7) * 8;
  int kdst[2], vdst[2];
#pragma unroll
  for (int p = 0; p < 2; ++p) {
    int kr = p * 32 + krow;
    kdst[p] = kr * 128 + ((lr ^ (kr & 7)) * 8);
    int vr = p * 64 + vrow;
    vdst[p] = vr * 64 + (((lane & 7) ^ (vr & 7)) * 8);
  }

  short8 kreg[2], vreg[2];
  auto issue = [&](int kvb) {
#pragma unroll
    for (int p = 0; p < 2; ++p)
      kreg[p] = *(const short8*)&kp[headq + (size_t)(kvb + p * 32 + krow) * Dc + kcol];
#pragma unroll
    for (int p = 0; p < 2; ++p)
      vreg[p] = *(const short8*)&vt[vbase + (size_t)(p * 64 + vrow) * Sc + kvb + vcol];
  };
  auto commit = [&]() {
#pragma unroll
    for (int p = 0; p < 2; ++p) *(short8*)&Ks[kdst[p]] = kreg[p];
#pragma unroll
    for (int p = 0; p < 2; ++p) *(short8*)&Vs[vdst[p]] = vreg[p];
  };

  issue(0);
  commit();
  __syncthreads();

  f32x4 o[2][8] = {};
  float mrun[2] = {-1e30f, -1e30f}, lrun[2] = {0.f, 0.f};
  const int ntiles = qb / 64 + 4;

  for (int t = 0; t < ntiles; ++t) {
    const bool active = (64 * t <= qw + 31);  // wave-uniform
    f32x4 sc[2][4];

    if (active) {
      __builtin_amdgcn_s_setprio(1);
#pragma unroll
      for (int nb = 0; nb < 4; ++nb) {
        f32x4 s0 = {}, s1 = {};
#pragma unroll
        for (int c = 0; c < 4; ++c) {
          short8 kf = *(const short8*)&Ks[(nb * 16 + lr) * 128 + (((c * 4 + g) ^ x7) << 3)];
          s0 = __builtin_amdgcn_mfma_f32_16x16x32_bf16(kf, qf[0][c], s0, 0, 0, 0);
          s1 = __builtin_amdgcn_mfma_f32_16x16x32_bf16(kf, qf[1][c], s1, 0, 0, 0);
        }
        sc[0][nb] = s0;
        sc[1][nb] = s1;
      }
      __builtin_amdgcn_s_setprio(0);
    }

    if (t + 1 < ntiles) issue((t + 1) * 64);

    if (active) {
      const bool domask = (64 * t + 63 > qw);
#pragma unroll
      for (int qs = 0; qs < 2; ++qs) {
        const int qg = qw + qs * 16 + lr;
        float mnb[4];
#pragma unroll
        for (int nb = 0; nb < 4; ++nb) {
          if (domask) {
#pragma unroll
            for (int r = 0; r < 4; ++r) {
              int kv = t * 64 + nb * 16 + rowl + r;
              if (kv > qg) sc[qs][nb][r] = -1e30f;
            }
          }
          mnb[nb] = fmaxf(fmaxf(sc[qs][nb][0], sc[qs][nb][1]),
                          fmaxf(sc[qs][nb][2], sc[qs][nb][3]));
        }
        float mt = fmaxf(fmaxf(mnb[0], mnb[1]), fmaxf(mnb[2], mnb[3]));
        mt = fmaxf(mt, __shfl_xor(mt, 16));
        mt = fmaxf(mt, __shfl_xor(mt, 32));

        // T13 defer-max: only rescale when tile max exceeds running max + 8
        if (!__all(mt <= mrun[qs] + 8.f)) {
          float mnew = fmaxf(mrun[qs], mt);
          float alpha = exp2s(mrun[qs] - mnew);
          mrun[qs] = mnew;
          lrun[qs] *= alpha;
          float al[4];
#pragma unroll
          for (int r = 0; r < 4; ++r) al[r] = __shfl(alpha, (lane & 48) | (rowl + r));
#pragma unroll
          for (int f = 0; f < 8; ++f)
#pragma unroll
            for (int r = 0; r < 4; ++r) o[qs][f][r] *= al[r];
        }
        const float mcur = mrun[qs];

        float lsnb[4];
#pragma unroll
        for (int nb = 0; nb < 4; ++nb) {
          float p0 = exp2s(sc[qs][nb][0] - mcur);
          float p1 = exp2s(sc[qs][nb][1] - mcur);
          float p2 = exp2s(sc[qs][nb][2] - mcur);
          float p3 = exp2s(sc[qs][nb][3] - mcur);
          lsnb[nb] = (p0 + p1) + (p2 + p3);
          uint2 w;
          w.x = pack2(p0, p1);
          w.y = pack2(p2, p3);
          *(uint2*)&Ps[wid][qs * 16 + lr][nb * 16 + rowl] = w;
        }
        float ls = (lsnb[0] + lsnb[1]) + (lsnb[2] + lsnb[3]);
        ls += __shfl_xor(ls, 16);
        ls += __shfl_xor(ls, 32);
        lrun[qs] += ls;
      }

      asm volatile("s_waitcnt lgkmcnt(0)" ::: "memory");
      __builtin_amdgcn_sched_barrier(0);

      __builtin_amdgcn_s_setprio(1);
#pragma unroll
      for (int kc = 0; kc < 2; ++kc) {
        short8 pf0 = *(const short8*)&Ps[wid][lr][kc * 32 + lk];
        short8 pf1 = *(const short8*)&Ps[wid][16 + lr][kc * 32 + lk];
#pragma unroll
        for (int nb = 0; nb < 8; ++nb) {
          short8 vf = *(const short8*)&Vs[(nb * 16 + lr) * 64 + (((kc * 4 + g) ^ x7) << 3)];
          o[0][nb] = __builtin_amdgcn_mfma_f32_16x16x32_bf16(pf0, vf, o[0][nb], 0, 0, 0);
          o[1][nb] = __builtin_amdgcn_mfma_f32_16x16x32_bf16(pf1, vf, o[1][nb], 0, 0, 0);
        }
      }
      __builtin_amdgcn_s_setprio(0);
    }

    __syncthreads();
    if (t + 1 < ntiles) commit();
    __syncthreads();
  }

#pragma unroll
  for (int qs = 0; qs < 2; ++qs) {
    float ld[4];
#pragma unroll
    for (int r = 0; r < 4; ++r) ld[r] = __shfl(lrun[qs], (lane & 48) | (rowl + r));
#pragma unroll
    for (int f = 0; f < 8; ++f)
#pragma unroll
      for (int r = 0; r < 4; ++r) {
        float v = o[qs][f][r] / ld[r];
        attn[headq + (size_t)(qw + qs * 16 + rowl + r) * Dc + f * 16 + lr] = f2bf(v);
      }
  }
}

// ---------------------------------------------------------------------------
extern "C" void kernel_launch(void* const* d_in, const int* in_sizes, int n_in,
                              void* d_out, int out_size, void* d_ws, size_t ws_size,
                              hipStream_t stream) {
  const float* Q = (const float*)d_in[0];
  const float* K = (const float*)d_in[1];
  const float* V = (const float*)d_in[2];
  // d_in[3] = mask (causal tril, structural — unused)
  const float* wq = (const float*)d_in[4];
  const float* bq = (const float*)d_in[5];
  const float* wk = (const float*)d_in[6];
  const float* bk = (const float*)d_in[7];
  const float* wv = (const float*)d_in[8];
  const float* bv = (const float*)d_in[9];
  const float* wo = (const float*)d_in[10];
  const float* bo = (const float*)d_in[11];

  char* ws = (char*)d_ws;
  const size_t WSZ = (size_t)Dc * Dc;
  const size_t XSZ = (size_t)Bc * Sc * Dc;
  short* WT = (short*)ws;
  short* QP = (short*)(ws + 4 * WSZ * 2);
  short* KP = (short*)(ws + 4 * WSZ * 2 + XSZ * 2);
  short* VT = (short*)(ws + 4 * WSZ * 2 + 2 * XSZ * 2);
  short* AT = (short*)(ws + 4 * WSZ * 2 + 3 * XSZ * 2);  // attn out
  // total: 8*WSZ + 8*XSZ bytes = 32 MiB + 128 MiB = 160 MiB

  transpose_w_kernel<<<dim3(Dc / 32, Dc / 32, 4), 256, 0, stream>>>(wq, wk, wv, wo, WT);

  qkv_gemm_kernel<<<768, 512, 0, stream>>>(Q, K, V, WT, bq, bk, bv, QP, KP, VT);

  attn_kernel<<<512, 512, 0, stream>>>(QP, KP, VT, AT);

  gemm_ring_kernel<1><<<(Bc * Sc / 256) * (Dc / 256), 512, 0, stream>>>(
      AT, WT + 3 * WSZ, bo, (float*)d_out, 1.f);
}

// Round 15
// 454.440 us; speedup vs baseline: 1.0858x; 1.0004x over previous
//
#include <hip/hip_runtime.h>
#include <hip/hip_bf16.h>

typedef __attribute__((ext_vector_type(8))) short short8;
typedef __attribute__((ext_vector_type(4))) float f32x4;

#define DEVINL __device__ __forceinline__

constexpr int Bc = 4, Sc = 2048, Dc = 2048, Hc = 16, DHc = 128;
// softmax in exp2 space: Q pre-scaled by 1/sqrt(128) * log2(e) in its GEMM
constexpr float SCALE2 = 0.08838834764831845f * 1.4426950408889634f;

DEVINL float exp2s(float x) { return __builtin_amdgcn_exp2f(x); }

DEVINL short f2bf(float f) {
  unsigned u = __builtin_bit_cast(unsigned, f);
  u = (u + 0x7fffu + ((u >> 16) & 1u)) >> 16;
  return (short)u;
}
DEVINL short bfc(float f) {
  __hip_bfloat16 h = __float2bfloat16(f);
  return __builtin_bit_cast(short, h);
}
DEVINL unsigned pack2(float a, float b) {
  return (unsigned)(unsigned short)f2bf(a) | ((unsigned)(unsigned short)f2bf(b) << 16);
}

// async global->LDS, 16B per lane; LDS dest = wave-uniform base + lane*16
DEVINL void gload16(const void* g, void* l) {
  __builtin_amdgcn_global_load_lds(
      (const __attribute__((address_space(1))) void*)g,
      (__attribute__((address_space(3))) void*)l, 16, 0, 0);
}

// ---------------- weight transpose + fp32->bf16:  wt[n][k] = w[k][n] -------
__global__ __launch_bounds__(256) void transpose_w_kernel(
    const float* __restrict__ w0, const float* __restrict__ w1,
    const float* __restrict__ w2, const float* __restrict__ w3,
    short* __restrict__ wt) {
  __shared__ float tile[32][33];
  const float* w = (blockIdx.z == 0) ? w0 : (blockIdx.z == 1) ? w1
                   : (blockIdx.z == 2) ? w2 : w3;
  short* out = wt + (size_t)blockIdx.z * Dc * Dc;
  int k0 = blockIdx.x * 32, n0 = blockIdx.y * 32;
  int t = threadIdx.x;
#pragma unroll
  for (int p = 0; p < 4; ++p) {
    int idx = p * 256 + t;
    int kr = idx >> 5, nc = idx & 31;
    tile[kr][nc] = w[(size_t)(k0 + kr) * Dc + n0 + nc];
  }
  __syncthreads();
#pragma unroll
  for (int p = 0; p < 4; ++p) {
    int idx = p * 256 + t;
    int nr = idx >> 5, kc = idx & 31;
    out[(size_t)(n0 + nr) * Dc + k0 + kc] = f2bf(tile[kc][nr]);
  }
}

// ---------------- merged QKV GEMM, A = f32 via global_load_lds -------------
// One 768-block dispatch = 3 x 256-block GEMMs (t = bid>>8 selects tensor).
// C = A_f32[M,K] @ Wt[N,K]^T + bias, scaled by oscale (Q gets SCALE2).
// A staged RAW f32 (3-slot ring, 96 KB), cvt to bf16 at fragment read.
// B bf16 3-slot ring (48 KB). slot = kt%3; stage(kt+2) at kt writes slot
// (kt-1)%3 whose reads are barrier-ordered complete (round-9 proof).
// 6 loads/kt: steady vmcnt(6) proves stage(kt); vmcnt(0) at kt=63 only.
// A LDS swizzle: 16B slot s at row r (128B rows) stored at s ^ (r&7).
// B LDS swizzle: s ^ ((r>>1)&3) on 64B rows.
// mode: 0 = bf16 [M,N] (scaled), 2 = bf16 V-transposed [B,H,DH,S]
__global__ __launch_bounds__(512, 1) void qkv_gemm_kernel(
    const float* __restrict__ Qin, const float* __restrict__ Kin,
    const float* __restrict__ Vin, const short* __restrict__ WTbase,
    const float* __restrict__ bq, const float* __restrict__ bk,
    const float* __restrict__ bv, short* __restrict__ QP,
    short* __restrict__ KP, short* __restrict__ VT) {
  __shared__ __align__(16) float As[3][256 * 32];
  __shared__ __align__(16) short Bs[3][256 * 32];
  const int tid = threadIdx.x, lane = tid & 63, wid = tid >> 6;
  const int wm = wid >> 2, wn = wid & 3;
  const int lr = lane & 15, g = lane >> 4;
  const int physg = (g ^ ((lr >> 1) & 3)) * 8;  // B swizzled read col (shorts)

  // tensor select
  const int tsel = blockIdx.x >> 8;
  const float* A = (tsel == 0) ? Qin : (tsel == 1) ? Kin : Vin;
  const short* Wt = WTbase + (size_t)tsel * Dc * Dc;
  const float* bias = (tsel == 0) ? bq : (tsel == 1) ? bk : bv;
  short* Cptr = (tsel == 0) ? QP : (tsel == 1) ? KP : VT;
  const float oscale = (tsel == 0) ? SCALE2 : 1.f;
  const int mode = (tsel == 2) ? 2 : 0;

  // XCD-aware bijective swizzle on local bid: 256 blocks, 8 XCDs, 32 per XCD
  const int bid = blockIdx.x & 255;  // (bid&7) == (blockIdx.x&7): XCD intact
  const int swz = (bid & 7) * 32 + (bid >> 3);
  const int m0 = (swz >> 3) * 256, n0 = (swz & 7) * 256;

  // A staging: 4 gloads/kt, each 8 rows of 128B; phys slot = lane&7
  const int arow8 = lane >> 3, aslot = lane & 7;
  auto stageA = [&](int kt) {
    char* slotbase = (char*)&As[kt % 3][0];
#pragma unroll
    for (int p = 0; p < 4; ++p) {
      int row = wid * 32 + p * 8 + arow8;
      int col = (aslot ^ (row & 7)) * 4;  // pre-swizzled source col (f32)
      gload16(&A[(size_t)(m0 + row) * Dc + kt * 32 + col],
              slotbase + (wid * 32 + p * 8) * 128);
    }
  };

  // B staging: 2 gloads/kt
  const int bsrow = lane >> 2;
  const int bscol = ((lane & 3) ^ ((lane >> 3) & 3)) * 8;
  const size_t bbase = (size_t)(n0 + wid * 32 + bsrow) * Dc + bscol;
  auto stageB = [&](int kt) {
    const short* src = &Wt[bbase + kt * 32];
    char* dst = (char*)&Bs[kt % 3][0] + wid * 32 * 64;
    gload16(src, dst);
    gload16(src + (size_t)16 * Dc, dst + 16 * 64);
  };

  // A fragment read: row-major [256][32] f32, slot-swizzled; cvt to bf16
  auto rdA = [&](const float* Ab, int row) -> short8 {
    const int r7 = row & 7;
    const char* rb = (const char*)(Ab + row * 32);
    f32x4 a0 = *(const f32x4*)(rb + (((2 * g) ^ r7) * 16));
    f32x4 a1 = *(const f32x4*)(rb + (((2 * g + 1) ^ r7) * 16));
    short8 r;
    r[0] = bfc(a0[0]); r[1] = bfc(a0[1]); r[2] = bfc(a0[2]); r[3] = bfc(a0[3]);
    r[4] = bfc(a1[0]); r[5] = bfc(a1[1]); r[6] = bfc(a1[2]); r[7] = bfc(a1[3]);
    return r;
  };

  f32x4 acc[8][4] = {};

  stageA(0); stageB(0);
  stageA(1); stageB(1);

  for (int kt = 0; kt < 64; ++kt) {
    // counted wait: own stage(kt) done; barrier => ALL waves' stage(kt) done.
    if (kt < 63) {
      asm volatile("s_waitcnt vmcnt(6)" ::: "memory");
    } else {
      asm volatile("s_waitcnt vmcnt(0)" ::: "memory");
    }
    __builtin_amdgcn_s_barrier();
    asm volatile("" ::: "memory");  // reads may not hoist above the barrier

    const float* Ab = &As[kt % 3][0];
    const short* Bb = &Bs[kt % 3][0];
    short8 afr[4], bfr[4], af2[4];
#pragma unroll
    for (int i = 0; i < 4; ++i) afr[i] = rdA(Ab, wm * 128 + i * 16 + lr);
#pragma unroll
    for (int j = 0; j < 4; ++j)
      bfr[j] = *(const short8*)&Bb[(wn * 64 + j * 16 + lr) * 32 + physg];
#pragma unroll
    for (int i = 0; i < 4; ++i) af2[i] = rdA(Ab, wm * 128 + 64 + i * 16 + lr);

    if (kt <= 61) { stageA(kt + 2); stageB(kt + 2); }  // writes slot (kt-1)%3

    __builtin_amdgcn_s_setprio(1);
#pragma unroll
    for (int i = 0; i < 4; ++i)
#pragma unroll
      for (int j = 0; j < 4; ++j)
        acc[i][j] = __builtin_amdgcn_mfma_f32_16x16x32_bf16(afr[i], bfr[j], acc[i][j], 0, 0, 0);
#pragma unroll
    for (int i = 0; i < 4; ++i)
#pragma unroll
      for (int j = 0; j < 4; ++j)
        acc[4 + i][j] = __builtin_amdgcn_mfma_f32_16x16x32_bf16(af2[i], bfr[j], acc[4 + i][j], 0, 0, 0);
    __builtin_amdgcn_s_setprio(0);
  }

  const int rowl = g * 4;
  if (mode == 0) {
#pragma unroll
    for (int bj = 0; bj < 4; ++bj) {
      const int gcol = n0 + wn * 64 + bj * 16 + lr;
      const float bv_ = bias[gcol];
#pragma unroll
      for (int ai = 0; ai < 8; ++ai)
#pragma unroll
        for (int r = 0; r < 4; ++r) {
          int grow = m0 + wm * 128 + ai * 16 + rowl + r;
          Cptr[(size_t)grow * Dc + gcol] = f2bf((acc[ai][bj][r] + bv_) * oscale);
        }
    }
  } else {
#pragma unroll
    for (int bj = 0; bj < 4; ++bj) {
      const int gcol = n0 + wn * 64 + bj * 16 + lr;
      const float bv_ = bias[gcol];
      const int hh = gcol >> 7, dh = gcol & (DHc - 1);
#pragma unroll
      for (int ai = 0; ai < 8; ++ai)
#pragma unroll
        for (int r = 0; r < 4; ++r) {
          int grow = m0 + wm * 128 + ai * 16 + rowl + r;
          int b4 = grow >> 11, ss = grow & (Sc - 1);
          Cptr[((((size_t)(b4 * Hc + hh) * DHc) + dh) << 11) + ss] =
              f2bf(acc[ai][bj][r] + bv_);
        }
    }
  }
}

// ---------------- 256x256 ring GEMM, A = bf16 (round-9 proven) -------------
// OUT_MODE: 1 = f32 [M,N]
template <int OUT_MODE>
__global__ __launch_bounds__(512, 1) void gemm_ring_kernel(
    const short* __restrict__ A, const short* __restrict__ Wt,
    const float* __restrict__ bias, void* __restrict__ Cptr, float oscale) {
  __shared__ __align__(16) short As[4][256 * 32];
  __shared__ __align__(16) short Bs[4][256 * 32];
  const int tid = threadIdx.x, lane = tid & 63, wid = tid >> 6;
  const int wm = wid >> 2, wn = wid & 3;
  const int lr = lane & 15, g = lane >> 4;
  const int physg = (g ^ ((lr >> 1) & 3)) * 8;

  const int bid = blockIdx.x;
  const int swz = (bid & 7) * 32 + (bid >> 3);
  const int m0 = (swz >> 3) * 256, n0 = (swz & 7) * 256;

  const int srow = lane >> 2;
  const int scol = ((lane & 3) ^ ((lane >> 3) & 3)) * 8;
  const size_t abase = (size_t)(m0 + wid * 32 + srow) * Dc + scol;
  const size_t bbase = (size_t)(n0 + wid * 32 + srow) * Dc + scol;
  const int ldof = wid * 32 * 64;

  auto stageA = [&](int kt) {
    const short* src = &A[abase + kt * 32];
    char* dst = (char*)&As[kt & 3][0] + ldof;
    gload16(src, dst);
    gload16(src + (size_t)16 * Dc, dst + 16 * 64);
  };
  auto stageB = [&](int kt) {
    const short* src = &Wt[bbase + kt * 32];
    char* dst = (char*)&Bs[kt & 3][0] + ldof;
    gload16(src, dst);
    gload16(src + (size_t)16 * Dc, dst + 16 * 64);
  };

  f32x4 acc[8][4] = {};

  stageA(0); stageB(0);
  stageA(1); stageB(1);
  stageA(2); stageB(2);

  for (int kt = 0; kt < 64; ++kt) {
    if (kt < 62) {
      asm volatile("s_waitcnt vmcnt(8)" ::: "memory");
    } else if (kt == 62) {
      asm volatile("s_waitcnt vmcnt(4)" ::: "memory");
    } else {
      asm volatile("s_waitcnt vmcnt(0)" ::: "memory");
    }
    __builtin_amdgcn_s_barrier();
    asm volatile("" ::: "memory");

    const short* Ab = &As[kt & 3][0];
    const short* Bb = &Bs[kt & 3][0];
    short8 afr[4], bfr[4], af2[4];
#pragma unroll
    for (int i = 0; i < 4; ++i)
      afr[i] = *(const short8*)&Ab[(wm * 128 + i * 16 + lr) * 32 + physg];
#pragma unroll
    for (int j = 0; j < 4; ++j)
      bfr[j] = *(const short8*)&Bb[(wn * 64 + j * 16 + lr) * 32 + physg];
#pragma unroll
    for (int i = 0; i < 4; ++i)
      af2[i] = *(const short8*)&Ab[(wm * 128 + 64 + i * 16 + lr) * 32 + physg];

    if (kt <= 60) { stageA(kt + 3); stageB(kt + 3); }

    __builtin_amdgcn_s_setprio(1);
#pragma unroll
    for (int i = 0; i < 4; ++i)
#pragma unroll
      for (int j = 0; j < 4; ++j)
        acc[i][j] = __builtin_amdgcn_mfma_f32_16x16x32_bf16(afr[i], bfr[j], acc[i][j], 0, 0, 0);
#pragma unroll
    for (int i = 0; i < 4; ++i)
#pragma unroll
      for (int j = 0; j < 4; ++j)
        acc[4 + i][j] = __builtin_amdgcn_mfma_f32_16x16x32_bf16(af2[i], bfr[j], acc[4 + i][j], 0, 0, 0);
    __builtin_amdgcn_s_setprio(0);
  }

  const int rowl = g * 4;
#pragma unroll
  for (int bj = 0; bj < 4; ++bj) {
    const int gcol = n0 + wn * 64 + bj * 16 + lr;
    const float bv = bias[gcol];
#pragma unroll
    for (int ai = 0; ai < 8; ++ai) {
#pragma unroll
      for (int r = 0; r < 4; ++r) {
        int grow = m0 + wm * 128 + ai * 16 + rowl + r;
        float v = (acc[ai][bj][r] + bv) * oscale;
        ((float*)Cptr)[(size_t)grow * Dc + gcol] = v;
      }
    }
  }
}

// ---------------- flash attention (causal), QB=256, 8 waves ----------------
// Swapped QK^T (lane owns q-rows) + T14 reg-staging + T13 defer-max.
// Q pre-scaled by SCALE2 in its projection -> scores already in log2 space.
// LDS XOR-swizzled 16B slots: Ks[row][s^=(row&7)], Vs[d][s^=(d&7)].
// Dispatch: LONGEST blocks FIRST (qi = 7-grp) so the 32-tile stragglers
// start immediately and short blocks fill the tail; heads XCD-clustered.
__global__ __launch_bounds__(512, 2) void attn_kernel(
    const short* __restrict__ qp, const short* __restrict__ kp,
    const short* __restrict__ vt, short* __restrict__ attn) {
  __shared__ __align__(16) short Ks[64 * 128];
  __shared__ __align__(16) short Vs[128 * 64];
  __shared__ __align__(16) short Ps[8][32][72];
  const int tid = threadIdx.x, lane = tid & 63, wid = tid >> 6;
  const int lr = lane & 15, g = lane >> 4, lk = g * 8, rowl = g * 4;
  const int d = blockIdx.x;
  const int xcd = d & 7, s = d >> 3;
  const int grp = s >> 3;
  const int qi = 7 - grp;  // longest-first: 7,6,5,4,3,2,1,0
  const int bh = xcd * 8 + (s & 7);
  const int b = bh >> 4, h = bh & 15;
  const int qb = qi * 256;
  const size_t headq = ((size_t)b * Sc) * Dc + (size_t)h * DHc;
  const size_t vbase = (((size_t)b * Hc + h) * DHc) << 11;
  const int qw = qb + wid * 32;
  const int x7 = lr & 7;

  short8 qf[2][4];
#pragma unroll
  for (int qs = 0; qs < 2; ++qs)
#pragma unroll
    for (int c = 0; c < 4; ++c)
      qf[qs][c] = *(const short8*)&qp[headq + (size_t)(qw + qs * 16 + lr) * Dc + c * 32 + lk];

  const int krow = wid * 4 + g;
  const int kcol = lr * 8;
  const int vrow = wid * 8 + (lane >> 3);
  const int vcol = (lane & 7) * 8;
  int kdst[2], vdst[2];
#pragma unroll
  for (int p = 0; p < 2; ++p) {
    int kr = p * 32 + krow;
    kdst[p] = kr * 128 + ((lr ^ (kr & 7)) * 8);
    int vr = p * 64 + vrow;
    vdst[p] = vr * 64 + (((lane & 7) ^ (vr & 7)) * 8);
  }

  short8 kreg[2], vreg[2];
  auto issue = [&](int kvb) {
#pragma unroll
    for (int p = 0; p < 2; ++p)
      kreg[p] = *(const short8*)&kp[headq + (size_t)(kvb + p * 32 + krow) * Dc + kcol];
#pragma unroll
    for (int p = 0; p < 2; ++p)
      vreg[p] = *(const short8*)&vt[vbase + (size_t)(p * 64 + vrow) * Sc + kvb + vcol];
  };
  auto commit = [&]() {
#pragma unroll
    for (int p = 0; p < 2; ++p) *(short8*)&Ks[kdst[p]] = kreg[p];
#pragma unroll
    for (int p = 0; p < 2; ++p) *(short8*)&Vs[vdst[p]] = vreg[p];
  };

  issue(0);
  commit();
  __syncthreads();

  f32x4 o[2][8] = {};
  float mrun[2] = {-1e30f, -1e30f}, lrun[2] = {0.f, 0.f};
  const int ntiles = qb / 64 + 4;

  for (int t = 0; t < ntiles; ++t) {
    const bool active = (64 * t <= qw + 31);  // wave-uniform
    f32x4 sc[2][4];

    if (active) {
      __builtin_amdgcn_s_setprio(1);
#pragma unroll
      for (int nb = 0; nb < 4; ++nb) {
        f32x4 s0 = {}, s1 = {};
#pragma unroll
        for (int c = 0; c < 4; ++c) {
          short8 kf = *(const short8*)&Ks[(nb * 16 + lr) * 128 + (((c * 4 + g) ^ x7) << 3)];
          s0 = __builtin_amdgcn_mfma_f32_16x16x32_bf16(kf, qf[0][c], s0, 0, 0, 0);
          s1 = __builtin_amdgcn_mfma_f32_16x16x32_bf16(kf, qf[1][c], s1, 0, 0, 0);
        }
        sc[0][nb] = s0;
        sc[1][nb] = s1;
      }
      __builtin_amdgcn_s_setprio(0);
    }

    if (t + 1 < ntiles) issue((t + 1) * 64);

    if (active) {
      const bool domask = (64 * t + 63 > qw);
#pragma unroll
      for (int qs = 0; qs < 2; ++qs) {
        const int qg = qw + qs * 16 + lr;
        float mnb[4];
#pragma unroll
        for (int nb = 0; nb < 4; ++nb) {
          if (domask) {
#pragma unroll
            for (int r = 0; r < 4; ++r) {
              int kv = t * 64 + nb * 16 + rowl + r;
              if (kv > qg) sc[qs][nb][r] = -1e30f;
            }
          }
          mnb[nb] = fmaxf(fmaxf(sc[qs][nb][0], sc[qs][nb][1]),
                          fmaxf(sc[qs][nb][2], sc[qs][nb][3]));
        }
        float mt = fmaxf(fmaxf(mnb[0], mnb[1]), fmaxf(mnb[2], mnb[3]));
        mt = fmaxf(mt, __shfl_xor(mt, 16));
        mt = fmaxf(mt, __shfl_xor(mt, 32));

        // T13 defer-max: only rescale when tile max exceeds running max + 8
        if (!__all(mt <= mrun[qs] + 8.f)) {
          float mnew = fmaxf(mrun[qs], mt);
          float alpha = exp2s(mrun[qs] - mnew);
          mrun[qs] = mnew;
          lrun[qs] *= alpha;
          float al[4];
#pragma unroll
          for (int r = 0; r < 4; ++r) al[r] = __shfl(alpha, (lane & 48) | (rowl + r));
#pragma unroll
          for (int f = 0; f < 8; ++f)
#pragma unroll
            for (int r = 0; r < 4; ++r) o[qs][f][r] *= al[r];
        }
        const float mcur = mrun[qs];

        float lsnb[4];
#pragma unroll
        for (int nb = 0; nb < 4; ++nb) {
          float p0 = exp2s(sc[qs][nb][0] - mcur);
          float p1 = exp2s(sc[qs][nb][1] - mcur);
          float p2 = exp2s(sc[qs][nb][2] - mcur);
          float p3 = exp2s(sc[qs][nb][3] - mcur);
          lsnb[nb] = (p0 + p1) + (p2 + p3);
          uint2 w;
          w.x = pack2(p0, p1);
          w.y = pack2(p2, p3);
          *(uint2*)&Ps[wid][qs * 16 + lr][nb * 16 + rowl] = w;
        }
        float ls = (lsnb[0] + lsnb[1]) + (lsnb[2] + lsnb[3]);
        ls += __shfl_xor(ls, 16);
        ls += __shfl_xor(ls, 32);
        lrun[qs] += ls;
      }

      asm volatile("s_waitcnt lgkmcnt(0)" ::: "memory");
      __builtin_amdgcn_sched_barrier(0);

      __builtin_amdgcn_s_setprio(1);
#pragma unroll
      for (int kc = 0; kc < 2; ++kc) {
        short8 pf0 = *(const short8*)&Ps[wid][lr][kc * 32 + lk];
        short8 pf1 = *(const short8*)&Ps[wid][16 + lr][kc * 32 + lk];
#pragma unroll
        for (int nb = 0; nb < 8; ++nb) {
          short8 vf = *(const short8*)&Vs[(nb * 16 + lr) * 64 + (((kc * 4 + g) ^ x7) << 3)];
          o[0][nb] = __builtin_amdgcn_mfma_f32_16x16x32_bf16(pf0, vf, o[0][nb], 0, 0, 0);
          o[1][nb] = __builtin_amdgcn_mfma_f32_16x16x32_bf16(pf1, vf, o[1][nb], 0, 0, 0);
        }
      }
      __builtin_amdgcn_s_setprio(0);
    }

    __syncthreads();
    if (t + 1 < ntiles) commit();
    __syncthreads();
  }

#pragma unroll
  for (int qs = 0; qs < 2; ++qs) {
    float ld[4];
#pragma unroll
    for (int r = 0; r < 4; ++r) ld[r] = __shfl(lrun[qs], (lane & 48) | (rowl + r));
#pragma unroll
    for (int f = 0; f < 8; ++f)
#pragma unroll
      for (int r = 0; r < 4; ++r) {
        float v = o[qs][f][r] / ld[r];
        attn[headq + (size_t)(qw + qs * 16 + rowl + r) * Dc + f * 16 + lr] = f2bf(v);
      }
  }
}

// ---------------------------------------------------------------------------
extern "C" void kernel_launch(void* const* d_in, const int* in_sizes, int n_in,
                              void* d_out, int out_size, void* d_ws, size_t ws_size,
                              hipStream_t stream) {
  const float* Q = (const float*)d_in[0];
  const float* K = (const float*)d_in[1];
  const float* V = (const float*)d_in[2];
  // d_in[3] = mask (causal tril, structural — unused)
  const float* wq = (const float*)d_in[4];
  const float* bq = (const float*)d_in[5];
  const float* wk = (const float*)d_in[6];
  const float* bk = (const float*)d_in[7];
  const float* wv = (const float*)d_in[8];
  const float* bv = (const float*)d_in[9];
  const float* wo = (const float*)d_in[10];
  const float* bo = (const float*)d_in[11];

  char* ws = (char*)d_ws;
  const size_t WSZ = (size_t)Dc * Dc;
  const size_t XSZ = (size_t)Bc * Sc * Dc;
  short* WT = (short*)ws;
  short* QP = (short*)(ws + 4 * WSZ * 2);
  short* KP = (short*)(ws + 4 * WSZ * 2 + XSZ * 2);
  short* VT = (short*)(ws + 4 * WSZ * 2 + 2 * XSZ * 2);
  short* AT = (short*)(ws + 4 * WSZ * 2 + 3 * XSZ * 2);  // attn out
  // total: 8*WSZ + 8*XSZ bytes = 32 MiB + 128 MiB = 160 MiB

  transpose_w_kernel<<<dim3(Dc / 32, Dc / 32, 4), 256, 0, stream>>>(wq, wk, wv, wo, WT);

  qkv_gemm_kernel<<<768, 512, 0, stream>>>(Q, K, V, WT, bq, bk, bv, QP, KP, VT);

  attn_kernel<<<512, 512, 0, stream>>>(QP, KP, VT, AT);

  gemm_ring_kernel<1><<<(Bc * Sc / 256) * (Dc / 256), 512, 0, stream>>>(
      AT, WT + 3 * WSZ, bo, (float*)d_out, 1.f);
}